// Round 1
// baseline (1143.451 us; speedup 1.0000x reference)
//
#include <hip/hip_runtime.h>
#include <math.h>

#define B_SZ 8
#define SEQ  4096
#define DM   64          // d_model
#define DI   128         // d_inner
#define NH   2           // heads
#define HD   64          // head dim (P)
#define DS   128         // d_state (S)
#define DIP  514         // in_proj out dim
#define CD   384         // conv dim
#define QC   32          // chunk length
#define NC   (SEQ/QC)    // 128 chunks
#define NR   (B_SZ*SEQ)  // 32768 rows

// ---------------- K1: in_proj GEMM  ZX[m][n] = sum_k X[m][k]*W[n][k] ----------------
__global__ __launch_bounds__(256) void k_inproj(const float* __restrict__ X,
                                                const float* __restrict__ W,
                                                float* __restrict__ ZX) {
    __shared__ float As[64][68];
    __shared__ float Bs[64][68];
    int m0 = blockIdx.x * 64, n0 = blockIdx.y * 64;
    int tid = threadIdx.x;
    int r = tid >> 2, q = tid & 3;
    for (int u = 0; u < 4; u++) {
        int k = q * 16 + u * 4;
        *(float4*)&As[r][k] = *(const float4*)(X + (size_t)(m0 + r) * 64 + k);
        int n = n0 + r;
        float4 bv = make_float4(0.f, 0.f, 0.f, 0.f);
        if (n < DIP) bv = *(const float4*)(W + (size_t)n * 64 + k);
        *(float4*)&Bs[r][k] = bv;
    }
    __syncthreads();
    int i0 = (tid >> 4) * 4, j0 = (tid & 15) * 4;
    float acc[4][4] = {};
    for (int k = 0; k < 64; k += 4) {
        float4 a[4], b[4];
#pragma unroll
        for (int u = 0; u < 4; u++) a[u] = *(float4*)&As[i0 + u][k];
#pragma unroll
        for (int v = 0; v < 4; v++) b[v] = *(float4*)&Bs[j0 + v][k];
#pragma unroll
        for (int u = 0; u < 4; u++)
#pragma unroll
            for (int v = 0; v < 4; v++)
                acc[u][v] += a[u].x * b[v].x + a[u].y * b[v].y + a[u].z * b[v].z + a[u].w * b[v].w;
    }
    for (int u = 0; u < 4; u++) {
        size_t row = m0 + i0 + u;
        for (int v = 0; v < 4; v++) {
            int n = n0 + j0 + v;
            if (n < DIP) ZX[row * DIP + n] = acc[u][v];
        }
    }
}

// ---------------- K2: depthwise causal conv(4) + bias + SiLU ----------------
__global__ __launch_bounds__(384) void k_conv(const float* __restrict__ ZX,
                                              const float* __restrict__ CW,
                                              const float* __restrict__ CB,
                                              float* __restrict__ XBC) {
    int r = blockIdx.x;           // row in [0, NR)
    int l = r & (SEQ - 1);
    int c = threadIdx.x;          // 0..383
    float w0 = CW[c * 4 + 0], w1 = CW[c * 4 + 1], w2 = CW[c * 4 + 2], w3 = CW[c * 4 + 3];
    size_t base = (size_t)r * DIP + 128 + c;
    float v = CB[c] + w3 * ZX[base];
    if (l >= 1) v += w2 * ZX[base - DIP];
    if (l >= 2) v += w1 * ZX[base - 2 * DIP];
    if (l >= 3) v += w0 * ZX[base - 3 * DIP];
    v = v / (1.f + __expf(-v));
    XBC[(size_t)r * CD + c] = v;
}

// ---------------- S1: per-(b,h,chunk): cumsum, G, M, SL, Y_intra ----------------
__global__ __launch_bounds__(256) void k_chunk1(
        const float* __restrict__ ZX, const float* __restrict__ XBC,
        const float* __restrict__ dtb, const float* __restrict__ Alog,
        const float* __restrict__ Dv,
        float* __restrict__ SL, float* __restrict__ TB,
        float* __restrict__ CUMB, float* __restrict__ YB) {
    __shared__ float Cs[QC][132];
    __shared__ float Bsh[QC][132];
    __shared__ float Xs[QC][68];
    __shared__ float Mt[QC][36];
    __shared__ float s_dt[QC], s_cum[QC], s_w[QC];
    int c = blockIdx.x;
    int bh = blockIdx.y;
    int b = bh >> 1, h = bh & 1;
    int l0 = c * QC;
    size_t rbase = (size_t)(b * SEQ + l0);
    int tid = threadIdx.x;

    if (tid < QC) {
        float raw = ZX[(rbase + tid) * DIP + 512 + h];
        float v = raw + dtb[h];
        float dt = (v > 20.f) ? v : log1pf(__expf(v));
        float A = -__expf(Alog[h]);
        float cum = dt * A;
        for (int off = 1; off < QC; off <<= 1) {
            float o = __shfl_up(cum, off);
            if (tid >= off) cum += o;
        }
        s_dt[tid] = dt;
        s_cum[tid] = cum;
        float T = __shfl(cum, QC - 1);
        s_w[tid] = __expf(T - cum) * dt;
        CUMB[((size_t)bh * NC + c) * QC + tid] = cum;
        if (tid == 0) TB[bh * NC + c] = T;
    }
    {
        int row = tid >> 3, q = tid & 7;
        size_t gb = (rbase + row) * CD;
        for (int u = 0; u < 4; u++) {
            int s = q * 16 + u * 4;
            *(float4*)&Cs[row][s]  = *(const float4*)(XBC + gb + 256 + s);
            *(float4*)&Bsh[row][s] = *(const float4*)(XBC + gb + 128 + s);
        }
        for (int u = 0; u < 2; u++) {
            int p = q * 8 + u * 4;
            *(float4*)&Xs[row][p] = *(const float4*)(XBC + gb + h * 64 + p);
        }
    }
    __syncthreads();
    // P1: G = C.Bt, then M (masked, decay-weighted), store transposed
    {
        int i0 = (tid >> 4) * 2, j0 = (tid & 15) * 2;
        float g[2][2] = {};
        for (int s = 0; s < DS; s += 4) {
            float4 cv0 = *(float4*)&Cs[i0][s],  cv1 = *(float4*)&Cs[i0 + 1][s];
            float4 bv0 = *(float4*)&Bsh[j0][s], bv1 = *(float4*)&Bsh[j0 + 1][s];
            g[0][0] += cv0.x * bv0.x + cv0.y * bv0.y + cv0.z * bv0.z + cv0.w * bv0.w;
            g[0][1] += cv0.x * bv1.x + cv0.y * bv1.y + cv0.z * bv1.z + cv0.w * bv1.w;
            g[1][0] += cv1.x * bv0.x + cv1.y * bv0.y + cv1.z * bv0.z + cv1.w * bv0.w;
            g[1][1] += cv1.x * bv1.x + cv1.y * bv1.y + cv1.z * bv1.z + cv1.w * bv1.w;
        }
        for (int u = 0; u < 2; u++)
            for (int v = 0; v < 2; v++) {
                int i = i0 + u, j = j0 + v;
                float m = 0.f;
                if (j <= i) m = g[u][v] * __expf(s_cum[i] - s_cum[j]) * s_dt[j];
                Mt[j][i] = m;
            }
    }
    // P2: SL[s][p] = sum_j w_j * B[j][s] * X[j][p]
    {
        int s0 = (tid >> 3) * 4, p0 = (tid & 7) * 8;
        float acc[4][8] = {};
        for (int j = 0; j < QC; j++) {
            float wj = s_w[j];
            float4 bv  = *(float4*)&Bsh[j][s0];
            float4 xv0 = *(float4*)&Xs[j][p0];
            float4 xv1 = *(float4*)&Xs[j][p0 + 4];
            float wb[4] = {wj * bv.x, wj * bv.y, wj * bv.z, wj * bv.w};
            float xv[8] = {xv0.x, xv0.y, xv0.z, xv0.w, xv1.x, xv1.y, xv1.z, xv1.w};
#pragma unroll
            for (int u = 0; u < 4; u++)
#pragma unroll
                for (int v = 0; v < 8; v++) acc[u][v] += wb[u] * xv[v];
        }
        size_t slb = ((size_t)bh * NC + c) * (DS * HD);
        for (int u = 0; u < 4; u++) {
            *(float4*)(SL + slb + (size_t)(s0 + u) * HD + p0)     = make_float4(acc[u][0], acc[u][1], acc[u][2], acc[u][3]);
            *(float4*)(SL + slb + (size_t)(s0 + u) * HD + p0 + 4) = make_float4(acc[u][4], acc[u][5], acc[u][6], acc[u][7]);
        }
    }
    __syncthreads();
    // P3: Y_intra = M @ X + D*x  -> YB
    {
        float dcoef = Dv[h];
        int i0 = (tid >> 4) * 2, p0 = (tid & 15) * 4;
        float acc[2][4];
        for (int u = 0; u < 2; u++) {
            float4 xv = *(float4*)&Xs[i0 + u][p0];
            acc[u][0] = dcoef * xv.x; acc[u][1] = dcoef * xv.y;
            acc[u][2] = dcoef * xv.z; acc[u][3] = dcoef * xv.w;
        }
        for (int j = 0; j < QC; j++) {
            float m0v = Mt[j][i0], m1v = Mt[j][i0 + 1];
            float4 xv = *(float4*)&Xs[j][p0];
            acc[0][0] += m0v * xv.x; acc[0][1] += m0v * xv.y; acc[0][2] += m0v * xv.z; acc[0][3] += m0v * xv.w;
            acc[1][0] += m1v * xv.x; acc[1][1] += m1v * xv.y; acc[1][2] += m1v * xv.z; acc[1][3] += m1v * xv.w;
        }
        for (int u = 0; u < 2; u++) {
            size_t row = rbase + i0 + u;
            *(float4*)(YB + row * DI + h * 64 + p0) = *(float4*)&acc[u][0];
        }
    }
}

// ---------------- S2: cross-chunk state recurrence (in-place: SL becomes H_start) ----------------
__global__ __launch_bounds__(256) void k_scan(float* __restrict__ SL, const float* __restrict__ TB) {
    int blk = blockIdx.x;
    int bh = blk >> 5;
    int sp = (blk & 31) * 256 + threadIdx.x;
    float hacc = 0.f;
    size_t base = (size_t)bh * NC * (DS * HD) + sp;
    for (int cc = 0; cc < NC; cc++) {
        size_t idx = base + (size_t)cc * (DS * HD);
        float slv = SL[idx];
        float dA = __expf(TB[bh * NC + cc]);
        SL[idx] = hacc;
        hacc = hacc * dA + slv;
    }
}

// ---------------- S3: Y_inter = exp(cum_i) * C_i . H  (accumulate into YB) ----------------
__global__ __launch_bounds__(256) void k_chunk2(const float* __restrict__ XBC,
                                                const float* __restrict__ SL,
                                                const float* __restrict__ CUMB,
                                                float* __restrict__ YB) {
    __shared__ float Ct[DS][36];
    __shared__ float Hs[DS][68];
    __shared__ float el[QC];
    int c = blockIdx.x, bh = blockIdx.y;
    int b = bh >> 1, h = bh & 1;
    int l0 = c * QC;
    size_t rbase = (size_t)(b * SEQ + l0);
    int tid = threadIdx.x;
    if (tid < QC) el[tid] = __expf(CUMB[((size_t)bh * NC + c) * QC + tid]);
    {
        int i = tid >> 3, q = tid & 7;
        size_t gb = (rbase + i) * CD + 256;
        for (int u = 0; u < 4; u++) {
            int s = q * 16 + u * 4;
            float4 v = *(const float4*)(XBC + gb + s);
            Ct[s][i] = v.x; Ct[s + 1][i] = v.y; Ct[s + 2][i] = v.z; Ct[s + 3][i] = v.w;
        }
    }
    {
        size_t hb = ((size_t)bh * NC + c) * (DS * HD);
        for (int rr = 0; rr < 32; rr++) {
            int e = rr * 256 + tid;
            Hs[e >> 6][e & 63] = SL[hb + e];
        }
    }
    __syncthreads();
    int i0 = (tid >> 4) * 2, p0 = (tid & 15) * 4;
    float acc[2][4] = {};
    for (int s = 0; s < DS; s++) {
        float c0 = Ct[s][i0], c1 = Ct[s][i0 + 1];
        float4 hv = *(float4*)&Hs[s][p0];
        acc[0][0] += c0 * hv.x; acc[0][1] += c0 * hv.y; acc[0][2] += c0 * hv.z; acc[0][3] += c0 * hv.w;
        acc[1][0] += c1 * hv.x; acc[1][1] += c1 * hv.y; acc[1][2] += c1 * hv.z; acc[1][3] += c1 * hv.w;
    }
    for (int u = 0; u < 2; u++) {
        size_t idx = (rbase + i0 + u) * DI + h * 64 + p0;
        float4 y = *(float4*)(YB + idx);
        float e = el[i0 + u];
        y.x += e * acc[u][0]; y.y += e * acc[u][1]; y.z += e * acc[u][2]; y.w += e * acc[u][3];
        *(float4*)(YB + idx) = y;
    }
}

// ---------------- S4: gate*SiLU(z), RMSNorm, out_proj, residual ----------------
__global__ __launch_bounds__(256) void k_out(const float* __restrict__ YB,
                                             const float* __restrict__ ZX,
                                             const float* __restrict__ NW,
                                             const float* __restrict__ OW,
                                             float* __restrict__ XR) {
    __shared__ float owt[DI][65];
    __shared__ float gbuf[4][DI];
    int tid = threadIdx.x;
    for (int rr = 0; rr < 32; rr++) {
        int e = rr * 256 + tid;
        int m = e >> 7, d = e & 127;
        owt[d][m] = OW[(size_t)m * DI + d];
    }
    int wid = tid >> 6, lane = tid & 63;
    int r = blockIdx.x * 4 + wid;
    size_t yb = (size_t)r * DI;
    size_t zb = (size_t)r * DIP;
    float y0 = YB[yb + lane], y1 = YB[yb + 64 + lane];
    float z0 = ZX[zb + lane], z1 = ZX[zb + 64 + lane];
    z0 = z0 / (1.f + __expf(-z0));
    z1 = z1 / (1.f + __expf(-z1));
    float g0 = y0 * z0, g1 = y1 * z1;
    float ss = g0 * g0 + g1 * g1;
    for (int off = 32; off > 0; off >>= 1) ss += __shfl_down(ss, off);
    ss = __shfl(ss, 0);
    float rms = rsqrtf(ss / 128.f + 1e-5f);
    gbuf[wid][lane]      = g0 * rms * NW[lane];
    gbuf[wid][64 + lane] = g1 * rms * NW[64 + lane];
    __syncthreads();
    float acc = 0.f;
    for (int d = 0; d < DI; d++) acc += gbuf[wid][d] * owt[d][lane];
    XR[(size_t)r * DM + lane] += acc;
}

extern "C" void kernel_launch(void* const* d_in, const int* in_sizes, int n_in,
                              void* d_out, int out_size, void* d_ws, size_t ws_size,
                              hipStream_t stream) {
    const float* x       = (const float*)d_in[0];
    const float* in_w    = (const float*)d_in[1];
    const float* conv_w  = (const float*)d_in[2];
    const float* conv_b  = (const float*)d_in[3];
    const float* dt_bias = (const float*)d_in[4];
    const float* A_log   = (const float*)d_in[5];
    const float* Dp      = (const float*)d_in[6];
    const float* norm_w  = (const float*)d_in[7];
    const float* out_w   = (const float*)d_in[8];
    float* out = (float*)d_out;
    float* ws  = (float*)d_ws;

    float* zx  = ws;                                   // NR*514
    float* xbc = zx  + (size_t)NR * DIP;               // NR*384
    float* sl  = xbc + (size_t)NR * CD;                // 16*NC*128*64
    float* yb  = sl  + (size_t)16 * NC * DS * HD;      // NR*128
    float* tb  = yb  + (size_t)NR * DI;                // 16*NC
    float* cb  = tb  + (size_t)16 * NC;                // 16*NC*32

    hipMemcpyAsync(out, x, (size_t)NR * DM * sizeof(float), hipMemcpyDeviceToDevice, stream);

    for (int layer = 0; layer < 4; layer++) {
        k_inproj<<<dim3(NR / 64, 9), 256, 0, stream>>>(out, in_w + (size_t)layer * DIP * DM, zx);
        k_conv<<<NR, CD, 0, stream>>>(zx, conv_w + (size_t)layer * CD * 4, conv_b + (size_t)layer * CD, xbc);
        k_chunk1<<<dim3(NC, 16), 256, 0, stream>>>(zx, xbc,
                dt_bias + layer * NH, A_log + layer * NH, Dp + layer * NH,
                sl, tb, cb, yb);
        k_scan<<<512, 256, 0, stream>>>(sl, tb);
        k_chunk2<<<dim3(NC, 16), 256, 0, stream>>>(xbc, sl, cb, yb);
        k_out<<<NR / 4, 256, 0, stream>>>(yb, zx, norm_w + layer * DI, out_w + (size_t)layer * DM * DI, out);
    }
}

// Round 2
// 718.750 us; speedup vs baseline: 1.5909x; 1.5909x over previous
//
#include <hip/hip_runtime.h>
#include <math.h>

#define B_SZ 8
#define SEQ  4096
#define DM   64
#define DI   128
#define NH   2
#define HD   64
#define DS   128
#define DIP  514
#define CD   384
#define QC   64
#define NC   64            // SEQ/QC
#define NR   (B_SZ*SEQ)

typedef __attribute__((ext_vector_type(8))) short bf16x8;
typedef __attribute__((ext_vector_type(4))) float f32x4;

__device__ __forceinline__ unsigned short f2bf(float f) {
    union { float f; unsigned int u; } x; x.f = f;
    unsigned int r = x.u + 0x7fffu + ((x.u >> 16) & 1u);
    return (unsigned short)(r >> 16);
}
__device__ __forceinline__ float bf2f(unsigned short h) {
    union { unsigned int u; float f; } x; x.u = ((unsigned int)h) << 16;
    return x.f;
}
// A-operand: lane holds A[r0+(lane&15)][k0 + (lane>>4)*8 + j], j=0..7 (row-major [m][k])
// B-operand: same pattern on [n][k]-major storage.
__device__ __forceinline__ bf16x8 fragld(const unsigned short* base, int r0, int k0, int ld) {
    int l = threadIdx.x & 63;
    return *(const bf16x8*)(base + (size_t)(r0 + (l & 15)) * ld + k0 + (l >> 4) * 8);
}

// ---------------- in_proj: ZX[m][n] = sum_k X[m][k] W[n][k], MFMA bf16 ----------------
__global__ __launch_bounds__(256) void k_inproj(const float* __restrict__ X,
                                                const float* __restrict__ W,
                                                float* __restrict__ ZX) {
    __shared__ unsigned short As[64][72];
    __shared__ unsigned short Bs[64][72];
    int m0 = blockIdx.x * 64, n0 = blockIdx.y * 64;
    int tid = threadIdx.x;
    int r = tid >> 2, q = tid & 3;
    for (int u = 0; u < 4; u++) {
        int k = q * 16 + u * 4;
        float4 av = *(const float4*)(X + (size_t)(m0 + r) * 64 + k);
        unsigned int p0 = f2bf(av.x) | ((unsigned int)f2bf(av.y) << 16);
        unsigned int p1 = f2bf(av.z) | ((unsigned int)f2bf(av.w) << 16);
        *(uint2*)&As[r][k] = make_uint2(p0, p1);
        int n = n0 + r;
        float4 bv = make_float4(0.f, 0.f, 0.f, 0.f);
        if (n < DIP) bv = *(const float4*)(W + (size_t)n * 64 + k);
        p0 = f2bf(bv.x) | ((unsigned int)f2bf(bv.y) << 16);
        p1 = f2bf(bv.z) | ((unsigned int)f2bf(bv.w) << 16);
        *(uint2*)&Bs[r][k] = make_uint2(p0, p1);
    }
    __syncthreads();
    int wid = tid >> 6, lane = tid & 63;
    int q4 = lane >> 4, c16 = lane & 15;
    for (int nt = 0; nt < 4; nt++) {
        f32x4 acc = {0.f, 0.f, 0.f, 0.f};
        for (int ks = 0; ks < 2; ks++) {
            bf16x8 a = fragld(&As[0][0], wid * 16, ks * 32, 72);
            bf16x8 b = fragld(&Bs[0][0], nt * 16, ks * 32, 72);
            acc = __builtin_amdgcn_mfma_f32_16x16x32_bf16(a, b, acc, 0, 0, 0);
        }
        int n = n0 + nt * 16 + c16;
        if (n < DIP) {
            for (int rr = 0; rr < 4; rr++) {
                int m = m0 + wid * 16 + q4 * 4 + rr;
                ZX[(size_t)m * DIP + n] = acc[rr];
            }
        }
    }
}

// ---------------- chunk1: dt/cum, fused conv+SiLU, G, M, Y_intra, SL^T (per b,chunk; both heads) ----------------
__global__ __launch_bounds__(512) void k_chunk1(
        const float* __restrict__ ZX,
        const float* __restrict__ CW, const float* __restrict__ CB,
        const float* __restrict__ dtb, const float* __restrict__ Alog,
        const float* __restrict__ Dv,
        unsigned short* __restrict__ SL, unsigned short* __restrict__ ECB,
        float* __restrict__ TB, float* __restrict__ YB) {
    __shared__ unsigned short sB[64][136];    // B  [j][s]
    __shared__ unsigned short sC[64][136];    // C  [i][s]
    __shared__ unsigned short sBt[128][72];   // Bt [s][j]
    __shared__ unsigned short sXt[128][72];   // Xt [p][j]   (p = global channel 0..127)
    __shared__ unsigned short sXw[128][72];   // Xt*w_{h(p)}[j]
    __shared__ unsigned short sM[2][64][72];  // M_h [i][j]
    __shared__ float s_cum[2][64], s_dt[2][64], s_w[2][64], s_e[2][64];

    int c = blockIdx.x, b = blockIdx.y;
    size_t rbase = (size_t)b * SEQ + c * QC;
    int tid = threadIdx.x;
    int wid = tid >> 6, lane = tid & 63;

    // Phase A: dt, inclusive cumsum(dt*A), w, e  (one wave per head)
    if (wid < 2) {
        int h = wid, j = lane;
        float raw = ZX[(rbase + j) * DIP + 512 + h] + dtb[h];
        float dt = (raw > 20.f) ? raw : log1pf(__expf(raw));
        float A = -__expf(Alog[h]);
        float x = dt * A;
        for (int off = 1; off < 64; off <<= 1) {
            float o = __shfl_up(x, off);
            if (lane >= off) x += o;
        }
        float T = __shfl(x, 63);
        s_dt[h][j] = dt;
        s_cum[h][j] = x;
        s_w[h][j] = __expf(T - x) * dt;
        s_e[h][j] = __expf(x);
        if (j == 0) TB[(b * 2 + h) * NC + c] = __expf(T);
    }
    __syncthreads();

    // Phase B: depthwise conv(4)+bias+SiLU from ZX, scatter to MFMA layouts
    size_t ecbase = ((size_t)(b * NC + c)) * 2 * 8192;
    for (int e = tid; e < 64 * 384; e += 512) {
        int jq = e >> 7;
        int j = jq / 3;
        int g = jq - j * 3;
        int cc = (g << 7) + (e & 127);
        int l = c * QC + j;
        const float* zp = ZX + (rbase + j) * DIP + 128 + cc;
        float w0 = CW[cc * 4], w1 = CW[cc * 4 + 1], w2 = CW[cc * 4 + 2], w3 = CW[cc * 4 + 3];
        float v = CB[cc] + w3 * zp[0];
        if (l >= 1) v += w2 * zp[-DIP];
        if (l >= 2) v += w1 * zp[-2 * DIP];
        if (l >= 3) v += w0 * zp[-3 * DIP];
        v = v / (1.f + __expf(-v));
        if (cc < 128) {
            sXt[cc][j] = f2bf(v);
            sXw[cc][j] = f2bf(v * s_w[cc >> 6][j]);
        } else if (cc < 256) {
            int s = cc - 128;
            sB[j][s] = f2bf(v);
            sBt[s][j] = f2bf(v);
        } else {
            int s = cc - 256;
            sC[j][s] = f2bf(v);
            ECB[ecbase + (size_t)j * 128 + s]        = f2bf(v * s_e[0][j]);
            ECB[ecbase + 8192 + (size_t)j * 128 + s] = f2bf(v * s_e[1][j]);
        }
    }
    __syncthreads();

    int q4 = lane >> 4, c16 = lane & 15;
    // Phase C: G[i][j] = sum_s C[i][s]B[j][s]; M_h = masked decay-weighted (16 tiles / 8 waves)
    for (int u = 0; u < 2; u++) {
        int t = wid * 2 + u;
        int it = t >> 2, jt = t & 3;
        f32x4 acc = {0.f, 0.f, 0.f, 0.f};
        for (int ks = 0; ks < 4; ks++) {
            bf16x8 a = fragld(&sC[0][0], it * 16, ks * 32, 136);
            bf16x8 bb = fragld(&sB[0][0], jt * 16, ks * 32, 136);
            acc = __builtin_amdgcn_mfma_f32_16x16x32_bf16(a, bb, acc, 0, 0, 0);
        }
        int j = jt * 16 + c16;
        for (int rr = 0; rr < 4; rr++) {
            int i = it * 16 + q4 * 4 + rr;
            float gv = acc[rr];
            for (int h = 0; h < 2; h++) {
                float m = 0.f;
                if (j <= i) m = gv * __expf(s_cum[h][i] - s_cum[h][j]) * s_dt[h][j];
                sM[h][i][j] = f2bf(m);
            }
        }
    }
    __syncthreads();

    // Phase D1: Y_intra = M_h @ X_h + D*x  (32 tiles / 8 waves)
    for (int u = 0; u < 4; u++) {
        int idx = wid * 4 + u;
        int h = idx >> 4, tt = idx & 15;
        int it = tt >> 2, pt = tt & 3;
        float dco = Dv[h];
        int pg = h * 64 + pt * 16 + c16;
        f32x4 acc;
        for (int rr = 0; rr < 4; rr++) {
            int i = it * 16 + q4 * 4 + rr;
            acc[rr] = dco * bf2f(sXt[pg][i]);
        }
        for (int ks = 0; ks < 2; ks++) {
            bf16x8 a = fragld(&sM[h][0][0], it * 16, ks * 32, 72);
            bf16x8 bb = fragld(&sXt[0][0], h * 64 + pt * 16, ks * 32, 72);
            acc = __builtin_amdgcn_mfma_f32_16x16x32_bf16(a, bb, acc, 0, 0, 0);
        }
        for (int rr = 0; rr < 4; rr++) {
            int i = it * 16 + q4 * 4 + rr;
            YB[(rbase + i) * DI + pg] = acc[rr];
        }
    }
    // Phase D2: SL^T[p][s] = sum_j Xw[p][j] Bt[s][j]  (64 tiles / 8 waves)
    size_t slbase = ((size_t)(b * NC + c)) * 16384;
    for (int u = 0; u < 8; u++) {
        int idx = wid * 8 + u;
        int ptl = idx >> 3, st = idx & 7;
        f32x4 acc = {0.f, 0.f, 0.f, 0.f};
        for (int ks = 0; ks < 2; ks++) {
            bf16x8 a = fragld(&sXw[0][0], ptl * 16, ks * 32, 72);
            bf16x8 bb = fragld(&sBt[0][0], st * 16, ks * 32, 72);
            acc = __builtin_amdgcn_mfma_f32_16x16x32_bf16(a, bb, acc, 0, 0, 0);
        }
        int s = st * 16 + c16;
        for (int rr = 0; rr < 4; rr++) {
            int p = ptl * 16 + q4 * 4 + rr;
            float v = acc[rr];
            float vn = __shfl_xor(v, 1);
            if (!(lane & 1)) {
                unsigned int pk = f2bf(v) | ((unsigned int)f2bf(vn) << 16);
                *(unsigned int*)(SL + slbase + (size_t)p * 128 + s) = pk;
            }
        }
    }
}

// ---------------- cross-chunk state scan (bf16 in-place, fp32 accum) ----------------
__global__ __launch_bounds__(256) void k_scan(unsigned short* __restrict__ SL,
                                              const float* __restrict__ TB) {
    int bid = blockIdx.x;
    int b = bid >> 6;
    int ps = (bid & 63) * 256 + threadIdx.x;   // (p,s) in [0,16384)
    int h = ps >> 13;
    const float* dAp = TB + (b * 2 + h) * NC;
    size_t base = (size_t)(b * NC) * 16384 + ps;
    float hacc = 0.f;
#pragma unroll 4
    for (int cc = 0; cc < NC; cc++) {
        size_t idx = base + (size_t)cc * 16384;
        float slv = bf2f(SL[idx]);
        SL[idx] = f2bf(hacc);
        hacc = hacc * dAp[cc] + slv;
    }
}

// ---------------- chunk2: YB += eC_h @ H_h  (MFMA, per b,chunk) ----------------
__global__ __launch_bounds__(256) void k_chunk2(const unsigned short* __restrict__ SL,
                                                const unsigned short* __restrict__ ECB,
                                                float* __restrict__ YB) {
    __shared__ unsigned short sH[128][136];   // Ht [p][s]
    __shared__ unsigned short sE[128][136];   // eC [(h*64+i)][s]
    int c = blockIdx.x, b = blockIdx.y;
    size_t rbase = (size_t)b * SEQ + c * QC;
    int tid = threadIdx.x;
    size_t base = ((size_t)(b * NC + c)) * 16384;
    for (int u = 0; u < 8; u++) {
        int e = u * 256 + tid;
        int row = e >> 4, cb8 = (e & 15) * 8;
        *(uint4*)&sH[row][cb8] = *(const uint4*)(SL + base + (size_t)row * 128 + cb8);
        *(uint4*)&sE[row][cb8] = *(const uint4*)(ECB + base + (size_t)row * 128 + cb8);
    }
    __syncthreads();
    int wid = tid >> 6, lane = tid & 63;
    int q4 = lane >> 4, c16 = lane & 15;
    for (int u = 0; u < 8; u++) {
        int idx = wid * 8 + u;
        int h = idx >> 4, tt = idx & 15;
        int it = tt >> 2, pt = tt & 3;
        f32x4 acc = {0.f, 0.f, 0.f, 0.f};
        for (int ks = 0; ks < 4; ks++) {
            bf16x8 a = fragld(&sE[0][0], h * 64 + it * 16, ks * 32, 136);
            bf16x8 bb = fragld(&sH[0][0], h * 64 + pt * 16, ks * 32, 136);
            acc = __builtin_amdgcn_mfma_f32_16x16x32_bf16(a, bb, acc, 0, 0, 0);
        }
        int pg = h * 64 + pt * 16 + c16;
        for (int rr = 0; rr < 4; rr++) {
            int i = it * 16 + q4 * 4 + rr;
            size_t o = (rbase + i) * DI + pg;
            YB[o] += acc[rr];
        }
    }
}

// ---------------- out: gate*SiLU(z), RMSNorm, out_proj (MFMA), residual ----------------
__global__ __launch_bounds__(256) void k_out(const float* __restrict__ YB,
                                             const float* __restrict__ ZX,
                                             const float* __restrict__ NW,
                                             const float* __restrict__ OW,
                                             float* __restrict__ XR) {
    __shared__ unsigned short sG[64][136];   // normed gated [row][d]
    __shared__ unsigned short sW[64][136];   // OW [m][d]
    int tid = threadIdx.x;
    size_t rbase = (size_t)blockIdx.x * 64;
    for (int u = 0; u < 8; u++) {
        int e4 = (u * 256 + tid) * 4;
        int m = e4 >> 7, d = e4 & 127;
        float4 v = *(const float4*)(OW + e4);
        unsigned int p0 = f2bf(v.x) | ((unsigned int)f2bf(v.y) << 16);
        unsigned int p1 = f2bf(v.z) | ((unsigned int)f2bf(v.w) << 16);
        *(uint2*)&sW[m][d] = make_uint2(p0, p1);
    }
    {
        int row = tid >> 2, part = tid & 3;
        int d0 = part * 32;
        size_t yo = (rbase + row) * DI + d0;
        size_t zo = (rbase + row) * DIP + d0;
        float gv[32];
        float ss = 0.f;
        for (int u = 0; u < 8; u++) {
            float4 y = *(const float4*)(YB + yo + u * 4);
            float4 z = *(const float4*)(ZX + zo + u * 4);
            float g0 = y.x * (z.x / (1.f + __expf(-z.x)));
            float g1 = y.y * (z.y / (1.f + __expf(-z.y)));
            float g2 = y.z * (z.z / (1.f + __expf(-z.z)));
            float g3 = y.w * (z.w / (1.f + __expf(-z.w)));
            gv[u * 4 + 0] = g0; gv[u * 4 + 1] = g1; gv[u * 4 + 2] = g2; gv[u * 4 + 3] = g3;
            ss += g0 * g0 + g1 * g1 + g2 * g2 + g3 * g3;
        }
        float o = __shfl_xor(ss, 1); ss += o;
        o = __shfl_xor(ss, 2); ss += o;
        float rms = rsqrtf(ss * (1.f / 128.f) + 1e-5f);
        for (int u = 0; u < 8; u++) {
            int d = d0 + u * 4;
            unsigned int p0 = f2bf(gv[u * 4] * rms * NW[d]) | ((unsigned int)f2bf(gv[u * 4 + 1] * rms * NW[d + 1]) << 16);
            unsigned int p1 = f2bf(gv[u * 4 + 2] * rms * NW[d + 2]) | ((unsigned int)f2bf(gv[u * 4 + 3] * rms * NW[d + 3]) << 16);
            *(uint2*)&sG[row][d] = make_uint2(p0, p1);
        }
    }
    __syncthreads();
    int wid = tid >> 6, lane = tid & 63;
    int q4 = lane >> 4, c16 = lane & 15;
    for (int nt = 0; nt < 4; nt++) {
        f32x4 acc = {0.f, 0.f, 0.f, 0.f};
        for (int ks = 0; ks < 4; ks++) {
            bf16x8 a = fragld(&sG[0][0], wid * 16, ks * 32, 136);
            bf16x8 bb = fragld(&sW[0][0], nt * 16, ks * 32, 136);
            acc = __builtin_amdgcn_mfma_f32_16x16x32_bf16(a, bb, acc, 0, 0, 0);
        }
        int n = nt * 16 + c16;
        for (int rr = 0; rr < 4; rr++) {
            int m = wid * 16 + q4 * 4 + rr;
            XR[(rbase + m) * DM + n] += acc[rr];
        }
    }
}

extern "C" void kernel_launch(void* const* d_in, const int* in_sizes, int n_in,
                              void* d_out, int out_size, void* d_ws, size_t ws_size,
                              hipStream_t stream) {
    const float* x       = (const float*)d_in[0];
    const float* in_w    = (const float*)d_in[1];
    const float* conv_w  = (const float*)d_in[2];
    const float* conv_b  = (const float*)d_in[3];
    const float* dt_bias = (const float*)d_in[4];
    const float* A_log   = (const float*)d_in[5];
    const float* Dp      = (const float*)d_in[6];
    const float* norm_w  = (const float*)d_in[7];
    const float* out_w   = (const float*)d_in[8];
    float* out = (float*)d_out;
    float* ws  = (float*)d_ws;

    float* zx = ws;                              // NR*514 f32
    float* yb = zx + (size_t)NR * DIP;           // NR*128 f32
    float* tb = yb + (size_t)NR * DI;            // 1024 f32 (exp(T) per bh,c)
    unsigned short* sl  = (unsigned short*)(tb + 1024);        // 8*64*16384 bf16
    unsigned short* ecb = sl + (size_t)B_SZ * NC * 16384;      // 8*64*16384 bf16

    hipMemcpyAsync(out, x, (size_t)NR * DM * sizeof(float), hipMemcpyDeviceToDevice, stream);

    for (int layer = 0; layer < 4; layer++) {
        k_inproj<<<dim3(NR / 64, 9), 256, 0, stream>>>(out, in_w + (size_t)layer * DIP * DM, zx);
        k_chunk1<<<dim3(NC, B_SZ), 512, 0, stream>>>(zx,
                conv_w + (size_t)layer * CD * 4, conv_b + (size_t)layer * CD,
                dt_bias + layer * NH, A_log + layer * NH, Dp + layer * NH,
                sl, ecb, tb, yb);
        k_scan<<<512, 256, 0, stream>>>(sl, tb);
        k_chunk2<<<dim3(NC, B_SZ), 256, 0, stream>>>(sl, ecb, yb);
        k_out<<<NR / 64, 256, 0, stream>>>(yb, zx, norm_w + layer * DI, out_w + (size_t)layer * DM * DI, out);
    }
}

// Round 3
// 399.245 us; speedup vs baseline: 2.8640x; 1.8003x over previous
//
#include <hip/hip_runtime.h>
#include <math.h>

#define B_SZ 8
#define SEQ  4096
#define DM   64
#define DI   128
#define NH   2
#define HD   64
#define DS   128
#define DIP  514
#define ZW   512           // bf16 ZX width (z + xBC), dt split out
#define CD   384
#define QC   64
#define NC   64            // SEQ/QC
#define NR   (B_SZ*SEQ)

typedef __attribute__((ext_vector_type(8))) short bf16x8;
typedef __attribute__((ext_vector_type(4))) float f32x4;

__device__ __forceinline__ unsigned short f2bf(float f) {
    union { float f; unsigned int u; } x; x.f = f;
    unsigned int r = x.u + 0x7fffu + ((x.u >> 16) & 1u);
    return (unsigned short)(r >> 16);
}
__device__ __forceinline__ float bf2f(unsigned short h) {
    union { unsigned int u; float f; } x; x.u = ((unsigned int)h) << 16;
    return x.f;
}
// A/B-operand: lane holds M[r0+(lane&15)][k0 + (lane>>4)*8 + j], j=0..7, row-major [m][k]
__device__ __forceinline__ bf16x8 fragld(const unsigned short* base, int r0, int k0, int ld) {
    int l = threadIdx.x & 63;
    return *(const bf16x8*)(base + (size_t)(r0 + (l & 15)) * ld + k0 + (l >> 4) * 8);
}

// ---------------- in_proj: bf16 ZXb (cols 0..511) + fp32 DT (cols 512..513) ----------------
__global__ __launch_bounds__(256) void k_inproj(const float* __restrict__ X,
                                                const float* __restrict__ W,
                                                unsigned short* __restrict__ ZXb,
                                                float* __restrict__ DT) {
    __shared__ unsigned short As[64][72];
    __shared__ unsigned short Bs[64][72];
    int m0 = blockIdx.x * 64, n0 = blockIdx.y * 64;
    int tid = threadIdx.x;
    int r = tid >> 2, q = tid & 3;
    for (int u = 0; u < 4; u++) {
        int k = q * 16 + u * 4;
        float4 av = *(const float4*)(X + (size_t)(m0 + r) * 64 + k);
        unsigned int p0 = f2bf(av.x) | ((unsigned int)f2bf(av.y) << 16);
        unsigned int p1 = f2bf(av.z) | ((unsigned int)f2bf(av.w) << 16);
        *(uint2*)&As[r][k] = make_uint2(p0, p1);
        int n = n0 + r;
        float4 bv = make_float4(0.f, 0.f, 0.f, 0.f);
        if (n < DIP) bv = *(const float4*)(W + (size_t)n * 64 + k);
        p0 = f2bf(bv.x) | ((unsigned int)f2bf(bv.y) << 16);
        p1 = f2bf(bv.z) | ((unsigned int)f2bf(bv.w) << 16);
        *(uint2*)&Bs[r][k] = make_uint2(p0, p1);
    }
    __syncthreads();
    int wid = tid >> 6, lane = tid & 63;
    int q4 = lane >> 4, c16 = lane & 15;
    int ntMax = (n0 < 512) ? 4 : 1;
    for (int nt = 0; nt < ntMax; nt++) {
        f32x4 acc = {0.f, 0.f, 0.f, 0.f};
        for (int ks = 0; ks < 2; ks++) {
            bf16x8 a = fragld(&As[0][0], wid * 16, ks * 32, 72);
            bf16x8 b = fragld(&Bs[0][0], nt * 16, ks * 32, 72);
            acc = __builtin_amdgcn_mfma_f32_16x16x32_bf16(a, b, acc, 0, 0, 0);
        }
        int n = n0 + nt * 16 + c16;
        if (n < 512) {
            for (int rr = 0; rr < 4; rr++) {
                int m = m0 + wid * 16 + q4 * 4 + rr;
                ZXb[(size_t)m * ZW + n] = f2bf(acc[rr]);
            }
        } else if (n < DIP) {
            for (int rr = 0; rr < 4; rr++) {
                int m = m0 + wid * 16 + q4 * 4 + rr;
                DT[(size_t)m * 2 + (n - 512)] = acc[rr];
            }
        }
    }
}

// ---------------- chunk1: dt/cum, fused conv+SiLU, G, M, Y_intra, SL^T ----------------
__global__ __launch_bounds__(512, 4) void k_chunk1(
        const unsigned short* __restrict__ ZXb, const float* __restrict__ DT,
        const float* __restrict__ CW, const float* __restrict__ CB,
        const float* __restrict__ dtb, const float* __restrict__ Alog,
        const float* __restrict__ Dv,
        unsigned short* __restrict__ SL, unsigned short* __restrict__ ECB,
        float* __restrict__ TB, float* __restrict__ YB) {
    __shared__ unsigned short sBt[128][72];   // Bt [s][j]           (D2 B-op)
    __shared__ unsigned short sXt[128][72];   // Xt [p][j]           (D1 B-op, D2 A-op via w)
    __shared__ unsigned short uBC[2][64][136];// [0]=B[j][s], [1]=C[i][s]; becomes sM[2][64][72]
    __shared__ float s_cum[2][64], s_dt[2][64], s_w[2][64], s_e[2][64];
    unsigned short (*sM)[64][72] = (unsigned short (*)[64][72])&uBC[0][0][0];

    int c = blockIdx.x, b = blockIdx.y;
    size_t rbase = (size_t)b * SEQ + c * QC;
    int tid = threadIdx.x;
    int wid = tid >> 6, lane = tid & 63;

    // Phase A: dt, inclusive cumsum(dt*A), w, e (one wave per head)
    if (wid < 2) {
        int h = wid, j = lane;
        float raw = DT[(rbase + j) * 2 + h] + dtb[h];
        float dt = (raw > 20.f) ? raw : log1pf(__expf(raw));
        float A = -__expf(Alog[h]);
        float x = dt * A;
        for (int off = 1; off < 64; off <<= 1) {
            float o = __shfl_up(x, off);
            if (lane >= off) x += o;
        }
        float T = __shfl(x, 63);
        s_dt[h][j] = dt;
        s_cum[h][j] = x;
        s_w[h][j] = __expf(T - x) * dt;
        s_e[h][j] = __expf(x);
        if (j == 0) TB[(b * 2 + h) * NC + c] = __expf(T);
    }
    __syncthreads();

    // Phase B: conv(4)+bias+SiLU from bf16 ZXb; scatter to MFMA layouts
    size_t ecbase = ((size_t)(b * NC + c)) * 2 * 8192;
    for (int e = tid; e < 64 * 96; e += 512) {
        int j = e / 96;
        int q = e - j * 96;
        int cc = q * 4;                 // conv channel 0..383
        int l = c * QC + j;
        const unsigned short* zp = ZXb + (rbase + j) * ZW + 128 + cc;
        uint2 a0 = *(const uint2*)zp;
        uint2 a1 = make_uint2(0, 0), a2 = make_uint2(0, 0), a3 = make_uint2(0, 0);
        if (l >= 1) a1 = *(const uint2*)(zp - ZW);
        if (l >= 2) a2 = *(const uint2*)(zp - 2 * ZW);
        if (l >= 3) a3 = *(const uint2*)(zp - 3 * ZW);
        float v[4];
#pragma unroll
        for (int u = 0; u < 4; u++) {
            unsigned int w0 = (u < 2) ? a0.x : a0.y;
            unsigned int w1 = (u < 2) ? a1.x : a1.y;
            unsigned int w2 = (u < 2) ? a2.x : a2.y;
            unsigned int w3 = (u < 2) ? a3.x : a3.y;
            int sh = (u & 1) * 16;
            float r0 = bf2f((unsigned short)(w0 >> sh));
            float r1 = bf2f((unsigned short)(w1 >> sh));
            float r2 = bf2f((unsigned short)(w2 >> sh));
            float r3 = bf2f((unsigned short)(w3 >> sh));
            float4 wv = *(const float4*)(CW + (cc + u) * 4);
            float t = CB[cc + u] + wv.w * r0 + wv.z * r1 + wv.y * r2 + wv.x * r3;
            v[u] = t / (1.f + __expf(-t));
        }
        if (cc < 128) {
#pragma unroll
            for (int u = 0; u < 4; u++) sXt[cc + u][j] = f2bf(v[u]);
        } else if (cc < 256) {
            int s = cc - 128;
            unsigned int p0 = f2bf(v[0]) | ((unsigned int)f2bf(v[1]) << 16);
            unsigned int p1 = f2bf(v[2]) | ((unsigned int)f2bf(v[3]) << 16);
            *(uint2*)&uBC[0][j][s] = make_uint2(p0, p1);
#pragma unroll
            for (int u = 0; u < 4; u++) sBt[s + u][j] = f2bf(v[u]);
        } else {
            int s = cc - 256;
            unsigned int p0 = f2bf(v[0]) | ((unsigned int)f2bf(v[1]) << 16);
            unsigned int p1 = f2bf(v[2]) | ((unsigned int)f2bf(v[3]) << 16);
            *(uint2*)&uBC[1][j][s] = make_uint2(p0, p1);
            float e0 = s_e[0][j], e1 = s_e[1][j];
            unsigned int q0 = f2bf(v[0] * e0) | ((unsigned int)f2bf(v[1] * e0) << 16);
            unsigned int q1 = f2bf(v[2] * e0) | ((unsigned int)f2bf(v[3] * e0) << 16);
            *(uint2*)(ECB + ecbase + (size_t)j * 128 + s) = make_uint2(q0, q1);
            q0 = f2bf(v[0] * e1) | ((unsigned int)f2bf(v[1] * e1) << 16);
            q1 = f2bf(v[2] * e1) | ((unsigned int)f2bf(v[3] * e1) << 16);
            *(uint2*)(ECB + ecbase + 8192 + (size_t)j * 128 + s) = make_uint2(q0, q1);
        }
    }
    __syncthreads();

    int q4 = lane >> 4, c16 = lane & 15;
    // Phase C: G = C.B^T in regs (16 tiles / 8 waves), then overlay sM
    f32x4 gacc[2];
    {
#pragma unroll
        for (int u = 0; u < 2; u++) {
            int t = wid * 2 + u;
            int it = t >> 2, jt = t & 3;
            f32x4 acc = {0.f, 0.f, 0.f, 0.f};
            for (int ks = 0; ks < 4; ks++) {
                bf16x8 a = fragld(&uBC[1][0][0], it * 16, ks * 32, 136);
                bf16x8 bb = fragld(&uBC[0][0][0], jt * 16, ks * 32, 136);
                acc = __builtin_amdgcn_mfma_f32_16x16x32_bf16(a, bb, acc, 0, 0, 0);
            }
            gacc[u] = acc;
        }
    }
    __syncthreads();
#pragma unroll
    for (int u = 0; u < 2; u++) {
        int t = wid * 2 + u;
        int it = t >> 2, jt = t & 3;
        int j = jt * 16 + c16;
        for (int rr = 0; rr < 4; rr++) {
            int i = it * 16 + q4 * 4 + rr;
            float gv = gacc[u][rr];
            for (int h = 0; h < 2; h++) {
                float m = 0.f;
                if (j <= i) m = gv * __expf(s_cum[h][i] - s_cum[h][j]) * s_dt[h][j];
                sM[h][i][j] = f2bf(m);
            }
        }
    }
    __syncthreads();

    // Phase D1: Y_intra = M_h @ X_h + D*x (32 tiles / 8 waves)
#pragma unroll
    for (int u = 0; u < 4; u++) {
        int idx = wid * 4 + u;
        int h = idx >> 4, tt = idx & 15;
        int it = tt >> 2, pt = tt & 3;
        float dco = Dv[h];
        int pg = h * 64 + pt * 16 + c16;
        f32x4 acc;
        for (int rr = 0; rr < 4; rr++) {
            int i = it * 16 + q4 * 4 + rr;
            acc[rr] = dco * bf2f(sXt[pg][i]);
        }
        for (int ks = 0; ks < 2; ks++) {
            bf16x8 a = fragld(&sM[h][0][0], it * 16, ks * 32, 72);
            bf16x8 bb = fragld(&sXt[0][0], h * 64 + pt * 16, ks * 32, 72);
            acc = __builtin_amdgcn_mfma_f32_16x16x32_bf16(a, bb, acc, 0, 0, 0);
        }
        for (int rr = 0; rr < 4; rr++) {
            int i = it * 16 + q4 * 4 + rr;
            YB[(rbase + i) * DI + pg] = acc[rr];
        }
    }
    // Phase D2: SL^T[p][s] = sum_j (X[p][j]*w_h[j]) Bt[s][j] (64 tiles / 8 waves)
    size_t slbase = ((size_t)(b * NC + c)) * 16384;
#pragma unroll
    for (int u = 0; u < 8; u++) {
        int idx = wid * 8 + u;
        int ptl = idx >> 3, st = idx & 7;
        int h = ptl >> 2;
        f32x4 acc = {0.f, 0.f, 0.f, 0.f};
        for (int ks = 0; ks < 2; ks++) {
            int jb = ks * 32 + (lane >> 4) * 8;
            bf16x8 a = fragld(&sXt[0][0], ptl * 16, ks * 32, 72);
            bf16x8 aw;
#pragma unroll
            for (int t = 0; t < 8; t++) aw[t] = (short)f2bf(bf2f((unsigned short)a[t]) * s_w[h][jb + t]);
            bf16x8 bb = fragld(&sBt[0][0], st * 16, ks * 32, 72);
            acc = __builtin_amdgcn_mfma_f32_16x16x32_bf16(aw, bb, acc, 0, 0, 0);
        }
        int s = st * 16 + c16;
        for (int rr = 0; rr < 4; rr++) {
            int p = ptl * 16 + q4 * 4 + rr;
            float vv = acc[rr];
            float vn = __shfl_xor(vv, 1);
            if (!(lane & 1)) {
                unsigned int pk = f2bf(vv) | ((unsigned int)f2bf(vn) << 16);
                *(unsigned int*)(SL + slbase + (size_t)p * 128 + s) = pk;
            }
        }
    }
}

// ---------------- cross-chunk state scan (bf16 in-place, fp32 accum) ----------------
__global__ __launch_bounds__(256) void k_scan(unsigned short* __restrict__ SL,
                                              const float* __restrict__ TB) {
    int bid = blockIdx.x;
    int b = bid >> 6;
    int ps = (bid & 63) * 256 + threadIdx.x;
    int h = ps >> 13;
    const float* dAp = TB + (b * 2 + h) * NC;
    size_t base = (size_t)(b * NC) * 16384 + ps;
    float hacc = 0.f;
#pragma unroll 8
    for (int cc = 0; cc < NC; cc++) {
        size_t idx = base + (size_t)cc * 16384;
        float slv = bf2f(SL[idx]);
        SL[idx] = f2bf(hacc);
        hacc = hacc * dAp[cc] + slv;
    }
}

// ---------------- chunk2: YB += eC_h @ H_h ----------------
__global__ __launch_bounds__(512) void k_chunk2(const unsigned short* __restrict__ SL,
                                                const unsigned short* __restrict__ ECB,
                                                float* __restrict__ YB) {
    __shared__ unsigned short sH[128][136];
    __shared__ unsigned short sE[128][136];
    int c = blockIdx.x, b = blockIdx.y;
    size_t rbase = (size_t)b * SEQ + c * QC;
    int tid = threadIdx.x;
    size_t base = ((size_t)(b * NC + c)) * 16384;
    for (int u = 0; u < 4; u++) {
        int e = u * 512 + tid;
        int row = e >> 4, cb8 = (e & 15) * 8;
        *(uint4*)&sH[row][cb8] = *(const uint4*)(SL + base + (size_t)row * 128 + cb8);
        *(uint4*)&sE[row][cb8] = *(const uint4*)(ECB + base + (size_t)row * 128 + cb8);
    }
    __syncthreads();
    int wid = tid >> 6, lane = tid & 63;
    int q4 = lane >> 4, c16 = lane & 15;
#pragma unroll
    for (int u = 0; u < 4; u++) {
        int idx = wid * 4 + u;
        int h = idx >> 4, tt = idx & 15;
        int it = tt >> 2, pt = tt & 3;
        f32x4 acc = {0.f, 0.f, 0.f, 0.f};
        for (int ks = 0; ks < 4; ks++) {
            bf16x8 a = fragld(&sE[0][0], h * 64 + it * 16, ks * 32, 136);
            bf16x8 bb = fragld(&sH[0][0], h * 64 + pt * 16, ks * 32, 136);
            acc = __builtin_amdgcn_mfma_f32_16x16x32_bf16(a, bb, acc, 0, 0, 0);
        }
        int pg = h * 64 + pt * 16 + c16;
        for (int rr = 0; rr < 4; rr++) {
            int i = it * 16 + q4 * 4 + rr;
            size_t o = (rbase + i) * DI + pg;
            YB[o] += acc[rr];
        }
    }
}

// ---------------- out: gate*SiLU(z), RMSNorm, out_proj (MFMA), residual ----------------
__global__ __launch_bounds__(256) void k_out(const float* __restrict__ YB,
                                             const unsigned short* __restrict__ ZXb,
                                             const float* __restrict__ NW,
                                             const float* __restrict__ OW,
                                             float* __restrict__ XR) {
    __shared__ unsigned short sG[64][136];
    __shared__ unsigned short sW[64][136];
    int tid = threadIdx.x;
    size_t rbase = (size_t)blockIdx.x * 64;
    for (int u = 0; u < 8; u++) {
        int e4 = (u * 256 + tid) * 4;
        int m = e4 >> 7, d = e4 & 127;
        float4 v = *(const float4*)(OW + e4);
        unsigned int p0 = f2bf(v.x) | ((unsigned int)f2bf(v.y) << 16);
        unsigned int p1 = f2bf(v.z) | ((unsigned int)f2bf(v.w) << 16);
        *(uint2*)&sW[m][d] = make_uint2(p0, p1);
    }
    {
        int row = tid >> 2, part = tid & 3;
        int d0 = part * 32;
        size_t yo = (rbase + row) * DI + d0;
        const unsigned short* zp = ZXb + (rbase + row) * ZW + d0;
        float zf[32];
        for (int u = 0; u < 4; u++) {
            uint4 zw = *(const uint4*)(zp + u * 8);
            unsigned int ww[4] = {zw.x, zw.y, zw.z, zw.w};
            for (int t = 0; t < 4; t++) {
                zf[u * 8 + t * 2]     = bf2f((unsigned short)(ww[t] & 0xffff));
                zf[u * 8 + t * 2 + 1] = bf2f((unsigned short)(ww[t] >> 16));
            }
        }
        float gv[32];
        float ss = 0.f;
        for (int u = 0; u < 8; u++) {
            float4 y = *(const float4*)(YB + yo + u * 4);
            float z0 = zf[u * 4], z1 = zf[u * 4 + 1], z2 = zf[u * 4 + 2], z3 = zf[u * 4 + 3];
            float g0 = y.x * (z0 / (1.f + __expf(-z0)));
            float g1 = y.y * (z1 / (1.f + __expf(-z1)));
            float g2 = y.z * (z2 / (1.f + __expf(-z2)));
            float g3 = y.w * (z3 / (1.f + __expf(-z3)));
            gv[u * 4 + 0] = g0; gv[u * 4 + 1] = g1; gv[u * 4 + 2] = g2; gv[u * 4 + 3] = g3;
            ss += g0 * g0 + g1 * g1 + g2 * g2 + g3 * g3;
        }
        float o = __shfl_xor(ss, 1); ss += o;
        o = __shfl_xor(ss, 2); ss += o;
        float rms = rsqrtf(ss * (1.f / 128.f) + 1e-5f);
        for (int u = 0; u < 8; u++) {
            int d = d0 + u * 4;
            unsigned int p0 = f2bf(gv[u * 4] * rms * NW[d]) | ((unsigned int)f2bf(gv[u * 4 + 1] * rms * NW[d + 1]) << 16);
            unsigned int p1 = f2bf(gv[u * 4 + 2] * rms * NW[d + 2]) | ((unsigned int)f2bf(gv[u * 4 + 3] * rms * NW[d + 3]) << 16);
            *(uint2*)&sG[row][d] = make_uint2(p0, p1);
        }
    }
    __syncthreads();
    int wid = tid >> 6, lane = tid & 63;
    int q4 = lane >> 4, c16 = lane & 15;
    for (int nt = 0; nt < 4; nt++) {
        f32x4 acc = {0.f, 0.f, 0.f, 0.f};
        for (int ks = 0; ks < 4; ks++) {
            bf16x8 a = fragld(&sG[0][0], wid * 16, ks * 32, 136);
            bf16x8 bb = fragld(&sW[0][0], nt * 16, ks * 32, 136);
            acc = __builtin_amdgcn_mfma_f32_16x16x32_bf16(a, bb, acc, 0, 0, 0);
        }
        int n = nt * 16 + c16;
        for (int rr = 0; rr < 4; rr++) {
            int m = wid * 16 + q4 * 4 + rr;
            XR[(rbase + m) * DM + n] += acc[rr];
        }
    }
}

extern "C" void kernel_launch(void* const* d_in, const int* in_sizes, int n_in,
                              void* d_out, int out_size, void* d_ws, size_t ws_size,
                              hipStream_t stream) {
    const float* x       = (const float*)d_in[0];
    const float* in_w    = (const float*)d_in[1];
    const float* conv_w  = (const float*)d_in[2];
    const float* conv_b  = (const float*)d_in[3];
    const float* dt_bias = (const float*)d_in[4];
    const float* A_log   = (const float*)d_in[5];
    const float* Dp      = (const float*)d_in[6];
    const float* norm_w  = (const float*)d_in[7];
    const float* out_w   = (const float*)d_in[8];
    float* out = (float*)d_out;
    float* ws  = (float*)d_ws;

    float* yb = ws;                                        // NR*128 f32
    float* dt = yb + (size_t)NR * DI;                      // NR*2 f32
    float* tb = dt + (size_t)NR * 2;                       // 1024 f32
    unsigned short* zxb = (unsigned short*)(tb + 1024);    // NR*512 bf16
    unsigned short* sl  = zxb + (size_t)NR * ZW;           // 8*64*16384 bf16
    unsigned short* ecb = sl + (size_t)B_SZ * NC * 16384;  // 8*64*16384 bf16

    hipMemcpyAsync(out, x, (size_t)NR * DM * sizeof(float), hipMemcpyDeviceToDevice, stream);

    for (int layer = 0; layer < 4; layer++) {
        k_inproj<<<dim3(NR / 64, 9), 256, 0, stream>>>(out, in_w + (size_t)layer * DIP * DM, zxb, dt);
        k_chunk1<<<dim3(NC, B_SZ), 512, 0, stream>>>(zxb, dt,
                conv_w + (size_t)layer * CD * 4, conv_b + (size_t)layer * CD,
                dt_bias + layer * NH, A_log + layer * NH, Dp + layer * NH,
                sl, ecb, tb, yb);
        k_scan<<<512, 256, 0, stream>>>(sl, tb);
        k_chunk2<<<dim3(NC, B_SZ), 512, 0, stream>>>(sl, ecb, yb);
        k_out<<<NR / 64, 256, 0, stream>>>(yb, zxb, norm_w + layer * DI, out_w + (size_t)layer * DM * DI, out);
    }
}

// Round 4
// 384.804 us; speedup vs baseline: 2.9715x; 1.0375x over previous
//
#include <hip/hip_runtime.h>
#include <math.h>

#define B_SZ 8
#define SEQ  4096
#define DM   64
#define DI   128
#define NH   2
#define HD   64
#define DS   128
#define DIP  514
#define ZW   512
#define CD   384
#define QC   64
#define NC   64
#define NR   (B_SZ*SEQ)
#define WPAD 576           // padded in_proj rows (bf16 weight buffer)

typedef __attribute__((ext_vector_type(8))) short bf16x8;
typedef __attribute__((ext_vector_type(4))) float f32x4;

__device__ __forceinline__ unsigned short f2bf(float f) {
    union { float f; unsigned int u; } x; x.f = f;
    unsigned int r = x.u + 0x7fffu + ((x.u >> 16) & 1u);
    return (unsigned short)(r >> 16);
}
__device__ __forceinline__ float bf2f(unsigned short h) {
    union { unsigned int u; float f; } x; x.u = ((unsigned int)h) << 16;
    return x.f;
}
// A/B-operand frag: lane holds M[r0+(lane&15)][k0 + (lane>>4)*8 + j], row-major [m][k]
__device__ __forceinline__ bf16x8 fragld(const unsigned short* base, int r0, int k0, int ld) {
    int l = threadIdx.x & 63;
    return *(const bf16x8*)(base + (size_t)(r0 + (l & 15)) * ld + k0 + (l >> 4) * 8);
}

// ---------------- weight pre-conversion (once per launch) ----------------
__global__ __launch_bounds__(256) void k_wcvt(const float* __restrict__ in_w,
                                              const float* __restrict__ out_w,
                                              unsigned short* __restrict__ Wb,
                                              unsigned short* __restrict__ OWb) {
    int idx = blockIdx.x * 256 + threadIdx.x;
    if (idx < 4 * WPAD * 64) {
        int l = idx / (WPAD * 64), r = idx % (WPAD * 64);
        int n = r >> 6, k = r & 63;
        float v = (n < DIP) ? in_w[(size_t)l * DIP * 64 + (size_t)n * 64 + k] : 0.f;
        Wb[idx] = f2bf(v);
    }
    if (idx < 4 * 64 * 128) OWb[idx] = f2bf(out_w[idx]);
}

// ---------------- residual stream f32 -> bf16 (layer 0 only) ----------------
__global__ __launch_bounds__(256) void k_xcvt(const float* __restrict__ X,
                                              unsigned short* __restrict__ Xb) {
    int idx = (blockIdx.x * 256 + threadIdx.x) * 4;
    float4 v = *(const float4*)(X + idx);
    uint2 p;
    p.x = f2bf(v.x) | ((unsigned int)f2bf(v.y) << 16);
    p.y = f2bf(v.z) | ((unsigned int)f2bf(v.w) << 16);
    *(uint2*)(Xb + idx) = p;
}

// ---------------- in_proj: LDS-free MFMA, bf16 in/out ----------------
__global__ __launch_bounds__(256) void k_inproj(const unsigned short* __restrict__ Xb,
                                                const unsigned short* __restrict__ Wb,
                                                unsigned short* __restrict__ ZXb,
                                                float* __restrict__ DT) {
    int m0 = blockIdx.x * 256;
    int n0 = blockIdx.y * 64;
    int tid = threadIdx.x;
    int wid = tid >> 6, lane = tid & 63;
    int q4 = lane >> 4, c16 = lane & 15;
    int mb = m0 + wid * 64;
    bf16x8 af[4][2];
#pragma unroll
    for (int mt = 0; mt < 4; mt++)
#pragma unroll
        for (int ks = 0; ks < 2; ks++)
            af[mt][ks] = *(const bf16x8*)(Xb + (size_t)(mb + mt * 16 + c16) * 64 + ks * 32 + q4 * 8);
    if (n0 < 512) {
#pragma unroll
        for (int nt = 0; nt < 4; nt++) {
            bf16x8 bf[2];
#pragma unroll
            for (int ks = 0; ks < 2; ks++)
                bf[ks] = *(const bf16x8*)(Wb + (size_t)(n0 + nt * 16 + c16) * 64 + ks * 32 + q4 * 8);
#pragma unroll
            for (int mt = 0; mt < 4; mt++) {
                f32x4 acc = {0.f, 0.f, 0.f, 0.f};
                acc = __builtin_amdgcn_mfma_f32_16x16x32_bf16(af[mt][0], bf[0], acc, 0, 0, 0);
                acc = __builtin_amdgcn_mfma_f32_16x16x32_bf16(af[mt][1], bf[1], acc, 0, 0, 0);
#pragma unroll
                for (int rr = 0; rr < 4; rr++) {
                    float v = acc[rr];
                    float vn = __shfl_xor(v, 1);
                    if (!(lane & 1)) {
                        unsigned int pk = f2bf(v) | ((unsigned int)f2bf(vn) << 16);
                        *(unsigned int*)(ZXb + (size_t)(mb + mt * 16 + q4 * 4 + rr) * ZW + n0 + nt * 16 + c16) = pk;
                    }
                }
            }
        }
    } else {
        bf16x8 bf[2];
#pragma unroll
        for (int ks = 0; ks < 2; ks++)
            bf[ks] = *(const bf16x8*)(Wb + (size_t)(512 + c16) * 64 + ks * 32 + q4 * 8);
#pragma unroll
        for (int mt = 0; mt < 4; mt++) {
            f32x4 acc = {0.f, 0.f, 0.f, 0.f};
            acc = __builtin_amdgcn_mfma_f32_16x16x32_bf16(af[mt][0], bf[0], acc, 0, 0, 0);
            acc = __builtin_amdgcn_mfma_f32_16x16x32_bf16(af[mt][1], bf[1], acc, 0, 0, 0);
            if (c16 < 2)
#pragma unroll
                for (int rr = 0; rr < 4; rr++)
                    DT[(size_t)(mb + mt * 16 + q4 * 4 + rr) * 2 + c16] = acc[rr];
        }
    }
}

// ---------------- chunk1: dt/cum, fused conv+SiLU, G, M, Y_intra(bf16), SL^T ----------------
__global__ __launch_bounds__(512, 4) void k_chunk1(
        const unsigned short* __restrict__ ZXb, const float* __restrict__ DT,
        const float* __restrict__ CW, const float* __restrict__ CB,
        const float* __restrict__ dtb, const float* __restrict__ Alog,
        const float* __restrict__ Dv,
        unsigned short* __restrict__ SL, unsigned short* __restrict__ ECB,
        float* __restrict__ TB, unsigned short* __restrict__ YBb) {
    __shared__ unsigned short sBt[128][72];
    __shared__ unsigned short sXt[128][72];
    __shared__ unsigned short uBC[2][64][136];
    __shared__ float s_cum[2][64], s_dt[2][64], s_w[2][64], s_e[2][64];
    unsigned short (*sM)[64][72] = (unsigned short (*)[64][72])&uBC[0][0][0];

    int c = blockIdx.x, b = blockIdx.y;
    size_t rbase = (size_t)b * SEQ + c * QC;
    int tid = threadIdx.x;
    int wid = tid >> 6, lane = tid & 63;

    if (wid < 2) {
        int h = wid, j = lane;
        float raw = DT[(rbase + j) * 2 + h] + dtb[h];
        float dt = (raw > 20.f) ? raw : log1pf(__expf(raw));
        float A = -__expf(Alog[h]);
        float x = dt * A;
        for (int off = 1; off < 64; off <<= 1) {
            float o = __shfl_up(x, off);
            if (lane >= off) x += o;
        }
        float T = __shfl(x, 63);
        s_dt[h][j] = dt;
        s_cum[h][j] = x;
        s_w[h][j] = __expf(T - x) * dt;
        s_e[h][j] = __expf(x);
        if (j == 0) TB[(b * 2 + h) * NC + c] = __expf(T);
    }
    __syncthreads();

    size_t ecbase = ((size_t)(b * NC + c)) * 2 * 8192;
    for (int e = tid; e < 64 * 96; e += 512) {
        int j = e / 96;
        int q = e - j * 96;
        int cc = q * 4;
        int l = c * QC + j;
        const unsigned short* zp = ZXb + (rbase + j) * ZW + 128 + cc;
        uint2 a0 = *(const uint2*)zp;
        uint2 a1 = make_uint2(0, 0), a2 = make_uint2(0, 0), a3 = make_uint2(0, 0);
        if (l >= 1) a1 = *(const uint2*)(zp - ZW);
        if (l >= 2) a2 = *(const uint2*)(zp - 2 * ZW);
        if (l >= 3) a3 = *(const uint2*)(zp - 3 * ZW);
        float v[4];
#pragma unroll
        for (int u = 0; u < 4; u++) {
            unsigned int w0 = (u < 2) ? a0.x : a0.y;
            unsigned int w1 = (u < 2) ? a1.x : a1.y;
            unsigned int w2 = (u < 2) ? a2.x : a2.y;
            unsigned int w3 = (u < 2) ? a3.x : a3.y;
            int sh = (u & 1) * 16;
            float r0 = bf2f((unsigned short)(w0 >> sh));
            float r1 = bf2f((unsigned short)(w1 >> sh));
            float r2 = bf2f((unsigned short)(w2 >> sh));
            float r3 = bf2f((unsigned short)(w3 >> sh));
            float4 wv = *(const float4*)(CW + (cc + u) * 4);
            float t = CB[cc + u] + wv.w * r0 + wv.z * r1 + wv.y * r2 + wv.x * r3;
            v[u] = t / (1.f + __expf(-t));
        }
        if (cc < 128) {
#pragma unroll
            for (int u = 0; u < 4; u++) sXt[cc + u][j] = f2bf(v[u]);
        } else if (cc < 256) {
            int s = cc - 128;
            unsigned int p0 = f2bf(v[0]) | ((unsigned int)f2bf(v[1]) << 16);
            unsigned int p1 = f2bf(v[2]) | ((unsigned int)f2bf(v[3]) << 16);
            *(uint2*)&uBC[0][j][s] = make_uint2(p0, p1);
#pragma unroll
            for (int u = 0; u < 4; u++) sBt[s + u][j] = f2bf(v[u]);
        } else {
            int s = cc - 256;
            unsigned int p0 = f2bf(v[0]) | ((unsigned int)f2bf(v[1]) << 16);
            unsigned int p1 = f2bf(v[2]) | ((unsigned int)f2bf(v[3]) << 16);
            *(uint2*)&uBC[1][j][s] = make_uint2(p0, p1);
            float e0 = s_e[0][j], e1 = s_e[1][j];
            unsigned int q0 = f2bf(v[0] * e0) | ((unsigned int)f2bf(v[1] * e0) << 16);
            unsigned int q1 = f2bf(v[2] * e0) | ((unsigned int)f2bf(v[3] * e0) << 16);
            *(uint2*)(ECB + ecbase + (size_t)j * 128 + s) = make_uint2(q0, q1);
            q0 = f2bf(v[0] * e1) | ((unsigned int)f2bf(v[1] * e1) << 16);
            q1 = f2bf(v[2] * e1) | ((unsigned int)f2bf(v[3] * e1) << 16);
            *(uint2*)(ECB + ecbase + 8192 + (size_t)j * 128 + s) = make_uint2(q0, q1);
        }
    }
    __syncthreads();

    int q4 = lane >> 4, c16 = lane & 15;
    f32x4 gacc[2];
#pragma unroll
    for (int u = 0; u < 2; u++) {
        int t = wid * 2 + u;
        int it = t >> 2, jt = t & 3;
        f32x4 acc = {0.f, 0.f, 0.f, 0.f};
        for (int ks = 0; ks < 4; ks++) {
            bf16x8 a = fragld(&uBC[1][0][0], it * 16, ks * 32, 136);
            bf16x8 bb = fragld(&uBC[0][0][0], jt * 16, ks * 32, 136);
            acc = __builtin_amdgcn_mfma_f32_16x16x32_bf16(a, bb, acc, 0, 0, 0);
        }
        gacc[u] = acc;
    }
    __syncthreads();
#pragma unroll
    for (int u = 0; u < 2; u++) {
        int t = wid * 2 + u;
        int it = t >> 2, jt = t & 3;
        int j = jt * 16 + c16;
        for (int rr = 0; rr < 4; rr++) {
            int i = it * 16 + q4 * 4 + rr;
            float gv = gacc[u][rr];
            for (int h = 0; h < 2; h++) {
                float m = 0.f;
                if (j <= i) m = gv * __expf(s_cum[h][i] - s_cum[h][j]) * s_dt[h][j];
                sM[h][i][j] = f2bf(m);
            }
        }
    }
    __syncthreads();

#pragma unroll
    for (int u = 0; u < 4; u++) {
        int idx = wid * 4 + u;
        int h = idx >> 4, tt = idx & 15;
        int it = tt >> 2, pt = tt & 3;
        float dco = Dv[h];
        int pg = h * 64 + pt * 16 + c16;
        f32x4 acc;
        for (int rr = 0; rr < 4; rr++) {
            int i = it * 16 + q4 * 4 + rr;
            acc[rr] = dco * bf2f(sXt[pg][i]);
        }
        for (int ks = 0; ks < 2; ks++) {
            bf16x8 a = fragld(&sM[h][0][0], it * 16, ks * 32, 72);
            bf16x8 bb = fragld(&sXt[0][0], h * 64 + pt * 16, ks * 32, 72);
            acc = __builtin_amdgcn_mfma_f32_16x16x32_bf16(a, bb, acc, 0, 0, 0);
        }
        for (int rr = 0; rr < 4; rr++) {
            int i = it * 16 + q4 * 4 + rr;
            float v = acc[rr];
            float vn = __shfl_xor(v, 1);
            if (!(lane & 1)) {
                unsigned int pk = f2bf(v) | ((unsigned int)f2bf(vn) << 16);
                *(unsigned int*)(YBb + (rbase + i) * DI + pg) = pk;
            }
        }
    }
    size_t slbase = ((size_t)(b * NC + c)) * 16384;
#pragma unroll
    for (int u = 0; u < 8; u++) {
        int idx = wid * 8 + u;
        int ptl = idx >> 3, st = idx & 7;
        int h = ptl >> 2;
        f32x4 acc = {0.f, 0.f, 0.f, 0.f};
        for (int ks = 0; ks < 2; ks++) {
            int jb = ks * 32 + (lane >> 4) * 8;
            bf16x8 a = fragld(&sXt[0][0], ptl * 16, ks * 32, 72);
            bf16x8 aw;
#pragma unroll
            for (int t = 0; t < 8; t++) aw[t] = (short)f2bf(bf2f((unsigned short)a[t]) * s_w[h][jb + t]);
            bf16x8 bb = fragld(&sBt[0][0], st * 16, ks * 32, 72);
            acc = __builtin_amdgcn_mfma_f32_16x16x32_bf16(aw, bb, acc, 0, 0, 0);
        }
        int s = st * 16 + c16;
        for (int rr = 0; rr < 4; rr++) {
            int p = ptl * 16 + q4 * 4 + rr;
            float vv = acc[rr];
            float vn = __shfl_xor(vv, 1);
            if (!(lane & 1)) {
                unsigned int pk = f2bf(vv) | ((unsigned int)f2bf(vn) << 16);
                *(unsigned int*)(SL + slbase + (size_t)p * 128 + s) = pk;
            }
        }
    }
}

// ---------------- cross-chunk state scan ----------------
__global__ __launch_bounds__(256) void k_scan(unsigned short* __restrict__ SL,
                                              const float* __restrict__ TB) {
    int bid = blockIdx.x;
    int b = bid >> 6;
    int ps = (bid & 63) * 256 + threadIdx.x;
    int h = ps >> 13;
    const float* dAp = TB + (b * 2 + h) * NC;
    size_t base = (size_t)(b * NC) * 16384 + ps;
    float hacc = 0.f;
#pragma unroll 8
    for (int cc = 0; cc < NC; cc++) {
        size_t idx = base + (size_t)cc * 16384;
        float slv = bf2f(SL[idx]);
        SL[idx] = f2bf(hacc);
        hacc = hacc * dAp[cc] + slv;
    }
}

// ---------------- fused: Y_inter + gate*SiLU(z) + RMSNorm + out_proj + residual + next-xb ----------------
__global__ __launch_bounds__(512, 2) void k_fused(
        const unsigned short* __restrict__ SL, const unsigned short* __restrict__ ECB,
        const unsigned short* __restrict__ YBb, const unsigned short* __restrict__ ZXb,
        const float* __restrict__ NW, const unsigned short* __restrict__ OWb,
        float* __restrict__ XR, unsigned short* __restrict__ Xbn) {
    __shared__ __attribute__((aligned(16))) unsigned short sH[128][136];
    __shared__ __attribute__((aligned(16))) unsigned short sE[128][136];
    float* sGf = (float*)&sH[0][0];                                   // [64][132] overlay
    unsigned short (*sG)[136] = (unsigned short (*)[136])&sE[0][0];   // [64][136] overlay

    int c = blockIdx.x, b = blockIdx.y;
    size_t rbase = (size_t)b * SEQ + c * QC;
    int tid = threadIdx.x;
    int wid = tid >> 6, lane = tid & 63;
    size_t base = ((size_t)(b * NC + c)) * 16384;
    for (int u = 0; u < 4; u++) {
        int e = u * 512 + tid;
        int row = e >> 4, cb8 = (e & 15) * 8;
        *(uint4*)&sH[row][cb8] = *(const uint4*)(SL + base + (size_t)row * 128 + cb8);
        *(uint4*)&sE[row][cb8] = *(const uint4*)(ECB + base + (size_t)row * 128 + cb8);
    }
    __syncthreads();
    int q4 = lane >> 4, c16 = lane & 15;

    float yv[4][4];
    int tit[4], tpg[4];
#pragma unroll
    for (int u = 0; u < 4; u++) {
        int idx = wid * 4 + u;
        int h = idx >> 4, tt = idx & 15;
        int it = tt >> 2, pt = tt & 3;
        f32x4 acc = {0.f, 0.f, 0.f, 0.f};
        for (int ks = 0; ks < 4; ks++) {
            bf16x8 a = fragld(&sE[0][0], h * 64 + it * 16, ks * 32, 136);
            bf16x8 bb = fragld(&sH[0][0], h * 64 + pt * 16, ks * 32, 136);
            acc = __builtin_amdgcn_mfma_f32_16x16x32_bf16(a, bb, acc, 0, 0, 0);
        }
        int pg = h * 64 + pt * 16 + c16;
        tit[u] = it; tpg[u] = pg;
        for (int rr = 0; rr < 4; rr++) {
            int i = it * 16 + q4 * 4 + rr;
            float y = acc[rr] + bf2f(YBb[(rbase + i) * DI + pg]);
            float z = bf2f(ZXb[(rbase + i) * ZW + pg]);
            yv[u][rr] = y * (z / (1.f + __expf(-z)));
        }
    }
    __syncthreads();
#pragma unroll
    for (int u = 0; u < 4; u++)
        for (int rr = 0; rr < 4; rr++) {
            int i = tit[u] * 16 + q4 * 4 + rr;
            sGf[i * 132 + tpg[u]] = yv[u][rr];
        }
    __syncthreads();
    {
        int row = tid >> 3, p0 = (tid & 7) * 16;
        float g[16];
        float ss = 0.f;
        for (int t2 = 0; t2 < 16; t2++) { g[t2] = sGf[row * 132 + p0 + t2]; ss += g[t2] * g[t2]; }
        ss += __shfl_xor(ss, 1);
        ss += __shfl_xor(ss, 2);
        ss += __shfl_xor(ss, 4);
        float rms = rsqrtf(ss * (1.f / 128.f) + 1e-5f);
        for (int t2 = 0; t2 < 16; t2 += 2) {
            unsigned int pk = f2bf(g[t2] * rms * NW[p0 + t2]) |
                              ((unsigned int)f2bf(g[t2 + 1] * rms * NW[p0 + t2 + 1]) << 16);
            *(unsigned int*)&sG[row][p0 + t2] = pk;
        }
    }
    __syncthreads();
#pragma unroll
    for (int u = 0; u < 2; u++) {
        int t = wid * 2 + u;
        int mt = t >> 2, nt = t & 3;
        f32x4 acc = {0.f, 0.f, 0.f, 0.f};
        for (int ks = 0; ks < 4; ks++) {
            bf16x8 a = fragld(&sG[0][0], mt * 16, ks * 32, 136);
            bf16x8 bb = *(const bf16x8*)(OWb + (size_t)(nt * 16 + c16) * 128 + ks * 32 + q4 * 8);
            acc = __builtin_amdgcn_mfma_f32_16x16x32_bf16(a, bb, acc, 0, 0, 0);
        }
        for (int rr = 0; rr < 4; rr++) {
            int m = mt * 16 + q4 * 4 + rr;
            int n = nt * 16 + c16;
            size_t o = (rbase + m) * DM + n;
            float v = XR[o] + acc[rr];
            XR[o] = v;
            float vn = __shfl_xor(v, 1);
            if (!(lane & 1)) {
                unsigned int pk = f2bf(v) | ((unsigned int)f2bf(vn) << 16);
                *(unsigned int*)(Xbn + o) = pk;
            }
        }
    }
}

extern "C" void kernel_launch(void* const* d_in, const int* in_sizes, int n_in,
                              void* d_out, int out_size, void* d_ws, size_t ws_size,
                              hipStream_t stream) {
    const float* x       = (const float*)d_in[0];
    const float* in_w    = (const float*)d_in[1];
    const float* conv_w  = (const float*)d_in[2];
    const float* conv_b  = (const float*)d_in[3];
    const float* dt_bias = (const float*)d_in[4];
    const float* A_log   = (const float*)d_in[5];
    const float* Dp      = (const float*)d_in[6];
    const float* norm_w  = (const float*)d_in[7];
    const float* out_w   = (const float*)d_in[8];
    float* out = (float*)d_out;
    float* ws  = (float*)d_ws;

    float* dt = ws;                                        // NR*2 f32
    float* tb = dt + (size_t)NR * 2;                       // 1024 f32
    unsigned short* zxb = (unsigned short*)(tb + 1024);    // NR*512
    unsigned short* ybb = zxb + (size_t)NR * ZW;           // NR*128
    unsigned short* sl  = ybb + (size_t)NR * DI;           // 8*64*16384
    unsigned short* ecb = sl + (size_t)B_SZ * NC * 16384;  // 8*64*16384
    unsigned short* xb  = ecb + (size_t)B_SZ * NC * 16384; // NR*64
    unsigned short* wb  = xb + (size_t)NR * DM;            // 4*576*64
    unsigned short* owb = wb + (size_t)4 * WPAD * 64;      // 4*64*128

    k_wcvt<<<(4 * WPAD * 64 + 255) / 256, 256, 0, stream>>>(in_w, out_w, wb, owb);
    k_xcvt<<<NR * DM / 1024, 256, 0, stream>>>(x, xb);
    hipMemcpyAsync(out, x, (size_t)NR * DM * sizeof(float), hipMemcpyDeviceToDevice, stream);

    for (int layer = 0; layer < 4; layer++) {
        k_inproj<<<dim3(NR / 256, 9), 256, 0, stream>>>(xb, wb + (size_t)layer * WPAD * 64, zxb, dt);
        k_chunk1<<<dim3(NC, B_SZ), 512, 0, stream>>>(zxb, dt,
                conv_w + (size_t)layer * CD * 4, conv_b + (size_t)layer * CD,
                dt_bias + layer * NH, A_log + layer * NH, Dp + layer * NH,
                sl, ecb, tb, ybb);
        k_scan<<<512, 256, 0, stream>>>(sl, tb);
        k_fused<<<dim3(NC, B_SZ), 512, 0, stream>>>(sl, ecb, ybb, zxb,
                norm_w + layer * DI, owb + (size_t)layer * 64 * 128, out, xb);
    }
}

// Round 5
// 370.304 us; speedup vs baseline: 3.0879x; 1.0392x over previous
//
#include <hip/hip_runtime.h>
#include <math.h>

#define B_SZ 8
#define SEQ  4096
#define DM   64
#define DI   128
#define NH   2
#define HD   64
#define DS   128
#define DIP  514
#define ZW   512
#define CD   384
#define QC   64
#define NC   64
#define NR   (B_SZ*SEQ)
#define WPAD 576

typedef __attribute__((ext_vector_type(8))) short bf16x8;
typedef __attribute__((ext_vector_type(4))) float f32x4;

__device__ __forceinline__ unsigned short f2bf(float f) {
    union { float f; unsigned int u; } x; x.f = f;
    unsigned int r = x.u + 0x7fffu + ((x.u >> 16) & 1u);
    return (unsigned short)(r >> 16);
}
__device__ __forceinline__ float bf2f(unsigned short h) {
    union { unsigned int u; float f; } x; x.u = ((unsigned int)h) << 16;
    return x.f;
}
// A/B-operand frag: lane holds M[r0+(lane&15)][k0 + (lane>>4)*8 + j], row-major [m][k]
__device__ __forceinline__ bf16x8 fragld(const unsigned short* base, int r0, int k0, int ld) {
    int l = threadIdx.x & 63;
    return *(const bf16x8*)(base + (size_t)(r0 + (l & 15)) * ld + k0 + (l >> 4) * 8);
}

// ---------------- weight pre-conversion (once per launch) ----------------
__global__ __launch_bounds__(256) void k_wcvt(const float* __restrict__ in_w,
                                              const float* __restrict__ out_w,
                                              unsigned short* __restrict__ Wb,
                                              unsigned short* __restrict__ OWb) {
    int idx = blockIdx.x * 256 + threadIdx.x;
    if (idx < 4 * WPAD * 64) {
        int l = idx / (WPAD * 64), r = idx % (WPAD * 64);
        int n = r >> 6, k = r & 63;
        float v = (n < DIP) ? in_w[(size_t)l * DIP * 64 + (size_t)n * 64 + k] : 0.f;
        Wb[idx] = f2bf(v);
    }
    if (idx < 4 * 64 * 128) OWb[idx] = f2bf(out_w[idx]);
}

// ---------------- residual stream f32 -> bf16 (layer 0 only) ----------------
__global__ __launch_bounds__(256) void k_xcvt(const float* __restrict__ X,
                                              unsigned short* __restrict__ Xb) {
    int idx = (blockIdx.x * 256 + threadIdx.x) * 4;
    float4 v = *(const float4*)(X + idx);
    uint2 p;
    p.x = f2bf(v.x) | ((unsigned int)f2bf(v.y) << 16);
    p.y = f2bf(v.z) | ((unsigned int)f2bf(v.w) << 16);
    *(uint2*)(Xb + idx) = p;
}

// ---------------- in_proj: LDS-free MFMA, bf16 in/out ----------------
__global__ __launch_bounds__(256) void k_inproj(const unsigned short* __restrict__ Xb,
                                                const unsigned short* __restrict__ Wb,
                                                unsigned short* __restrict__ ZXb,
                                                float* __restrict__ DT) {
    int m0 = blockIdx.x * 256;
    int n0 = blockIdx.y * 64;
    int tid = threadIdx.x;
    int wid = tid >> 6, lane = tid & 63;
    int q4 = lane >> 4, c16 = lane & 15;
    int mb = m0 + wid * 64;
    bf16x8 af[4][2];
#pragma unroll
    for (int mt = 0; mt < 4; mt++)
#pragma unroll
        for (int ks = 0; ks < 2; ks++)
            af[mt][ks] = *(const bf16x8*)(Xb + (size_t)(mb + mt * 16 + c16) * 64 + ks * 32 + q4 * 8);
    if (n0 < 512) {
#pragma unroll
        for (int nt = 0; nt < 4; nt++) {
            bf16x8 bf[2];
#pragma unroll
            for (int ks = 0; ks < 2; ks++)
                bf[ks] = *(const bf16x8*)(Wb + (size_t)(n0 + nt * 16 + c16) * 64 + ks * 32 + q4 * 8);
#pragma unroll
            for (int mt = 0; mt < 4; mt++) {
                f32x4 acc = {0.f, 0.f, 0.f, 0.f};
                acc = __builtin_amdgcn_mfma_f32_16x16x32_bf16(af[mt][0], bf[0], acc, 0, 0, 0);
                acc = __builtin_amdgcn_mfma_f32_16x16x32_bf16(af[mt][1], bf[1], acc, 0, 0, 0);
#pragma unroll
                for (int rr = 0; rr < 4; rr++) {
                    float v = acc[rr];
                    float vn = __shfl_xor(v, 1);
                    if (!(lane & 1)) {
                        unsigned int pk = f2bf(v) | ((unsigned int)f2bf(vn) << 16);
                        *(unsigned int*)(ZXb + (size_t)(mb + mt * 16 + q4 * 4 + rr) * ZW + n0 + nt * 16 + c16) = pk;
                    }
                }
            }
        }
    } else {
        bf16x8 bf[2];
#pragma unroll
        for (int ks = 0; ks < 2; ks++)
            bf[ks] = *(const bf16x8*)(Wb + (size_t)(512 + c16) * 64 + ks * 32 + q4 * 8);
#pragma unroll
        for (int mt = 0; mt < 4; mt++) {
            f32x4 acc = {0.f, 0.f, 0.f, 0.f};
            acc = __builtin_amdgcn_mfma_f32_16x16x32_bf16(af[mt][0], bf[0], acc, 0, 0, 0);
            acc = __builtin_amdgcn_mfma_f32_16x16x32_bf16(af[mt][1], bf[1], acc, 0, 0, 0);
            if (c16 < 2)
#pragma unroll
                for (int rr = 0; rr < 4; rr++)
                    DT[(size_t)(mb + mt * 16 + q4 * 4 + rr) * 2 + c16] = acc[rr];
        }
    }
}

// ---------------- chunk1: dt/cum, fused conv+SiLU, G, M, Y_intra(bf16), SL^T, CB, EB ----------------
__global__ __launch_bounds__(512, 4) void k_chunk1(
        const unsigned short* __restrict__ ZXb, const float* __restrict__ DT,
        const float* __restrict__ CW, const float* __restrict__ CB,
        const float* __restrict__ dtb, const float* __restrict__ Alog,
        const float* __restrict__ Dv,
        unsigned short* __restrict__ SL, unsigned short* __restrict__ CBuf,
        float* __restrict__ EB,
        float* __restrict__ TB, unsigned short* __restrict__ YBb) {
    __shared__ unsigned short sBt[128][72];
    __shared__ unsigned short sXt[128][72];
    __shared__ unsigned short uBC[2][64][136];
    __shared__ float s_cum[2][64], s_dt[2][64], s_w[2][64];
    unsigned short (*sM)[64][72] = (unsigned short (*)[64][72])&uBC[0][0][0];

    int c = blockIdx.x, b = blockIdx.y;
    size_t rbase = (size_t)b * SEQ + c * QC;
    int tid = threadIdx.x;
    int wid = tid >> 6, lane = tid & 63;

    if (wid < 2) {
        int h = wid, j = lane;
        float raw = DT[(rbase + j) * 2 + h] + dtb[h];
        float dt = (raw > 20.f) ? raw : log1pf(__expf(raw));
        float A = -__expf(Alog[h]);
        float x = dt * A;
        for (int off = 1; off < 64; off <<= 1) {
            float o = __shfl_up(x, off);
            if (lane >= off) x += o;
        }
        float T = __shfl(x, 63);
        s_dt[h][j] = dt;
        s_cum[h][j] = x;
        s_w[h][j] = __expf(T - x) * dt;
        EB[((size_t)(b * NC + c)) * 128 + h * 64 + j] = __expf(x);
        if (j == 0) TB[(b * 2 + h) * NC + c] = __expf(T);
    }
    __syncthreads();

    size_t cbbase = ((size_t)(b * NC + c)) * 8192;
    for (int e = tid; e < 64 * 96; e += 512) {
        int j = e / 96;
        int q = e - j * 96;
        int cc = q * 4;
        int l = c * QC + j;
        const unsigned short* zp = ZXb + (rbase + j) * ZW + 128 + cc;
        uint2 a0 = *(const uint2*)zp;
        uint2 a1 = make_uint2(0, 0), a2 = make_uint2(0, 0), a3 = make_uint2(0, 0);
        if (l >= 1) a1 = *(const uint2*)(zp - ZW);
        if (l >= 2) a2 = *(const uint2*)(zp - 2 * ZW);
        if (l >= 3) a3 = *(const uint2*)(zp - 3 * ZW);
        float v[4];
#pragma unroll
        for (int u = 0; u < 4; u++) {
            unsigned int w0 = (u < 2) ? a0.x : a0.y;
            unsigned int w1 = (u < 2) ? a1.x : a1.y;
            unsigned int w2 = (u < 2) ? a2.x : a2.y;
            unsigned int w3 = (u < 2) ? a3.x : a3.y;
            int sh = (u & 1) * 16;
            float r0 = bf2f((unsigned short)(w0 >> sh));
            float r1 = bf2f((unsigned short)(w1 >> sh));
            float r2 = bf2f((unsigned short)(w2 >> sh));
            float r3 = bf2f((unsigned short)(w3 >> sh));
            float4 wv = *(const float4*)(CW + (cc + u) * 4);
            float t = CB[cc + u] + wv.w * r0 + wv.z * r1 + wv.y * r2 + wv.x * r3;
            v[u] = t / (1.f + __expf(-t));
        }
        if (cc < 128) {
#pragma unroll
            for (int u = 0; u < 4; u++) sXt[cc + u][j] = f2bf(v[u]);
        } else if (cc < 256) {
            int s = cc - 128;
            unsigned int p0 = f2bf(v[0]) | ((unsigned int)f2bf(v[1]) << 16);
            unsigned int p1 = f2bf(v[2]) | ((unsigned int)f2bf(v[3]) << 16);
            *(uint2*)&uBC[0][j][s] = make_uint2(p0, p1);
#pragma unroll
            for (int u = 0; u < 4; u++) sBt[s + u][j] = f2bf(v[u]);
        } else {
            int s = cc - 256;
            unsigned int p0 = f2bf(v[0]) | ((unsigned int)f2bf(v[1]) << 16);
            unsigned int p1 = f2bf(v[2]) | ((unsigned int)f2bf(v[3]) << 16);
            *(uint2*)&uBC[1][j][s] = make_uint2(p0, p1);
            *(uint2*)(CBuf + cbbase + (size_t)j * 128 + s) = make_uint2(p0, p1);
        }
    }
    __syncthreads();

    int q4 = lane >> 4, c16 = lane & 15;
    f32x4 gacc[2];
#pragma unroll
    for (int u = 0; u < 2; u++) {
        int t = wid * 2 + u;
        int it = t >> 2, jt = t & 3;
        f32x4 acc = {0.f, 0.f, 0.f, 0.f};
        for (int ks = 0; ks < 4; ks++) {
            bf16x8 a = fragld(&uBC[1][0][0], it * 16, ks * 32, 136);
            bf16x8 bb = fragld(&uBC[0][0][0], jt * 16, ks * 32, 136);
            acc = __builtin_amdgcn_mfma_f32_16x16x32_bf16(a, bb, acc, 0, 0, 0);
        }
        gacc[u] = acc;
    }
    __syncthreads();
#pragma unroll
    for (int u = 0; u < 2; u++) {
        int t = wid * 2 + u;
        int it = t >> 2, jt = t & 3;
        int j = jt * 16 + c16;
        for (int rr = 0; rr < 4; rr++) {
            int i = it * 16 + q4 * 4 + rr;
            float gv = gacc[u][rr];
            for (int h = 0; h < 2; h++) {
                float m = 0.f;
                if (j <= i) m = gv * __expf(s_cum[h][i] - s_cum[h][j]) * s_dt[h][j];
                sM[h][i][j] = f2bf(m);
            }
        }
    }
    __syncthreads();

#pragma unroll
    for (int u = 0; u < 4; u++) {
        int idx = wid * 4 + u;
        int h = idx >> 4, tt = idx & 15;
        int it = tt >> 2, pt = tt & 3;
        float dco = Dv[h];
        int pg = h * 64 + pt * 16 + c16;
        f32x4 acc;
        for (int rr = 0; rr < 4; rr++) {
            int i = it * 16 + q4 * 4 + rr;
            acc[rr] = dco * bf2f(sXt[pg][i]);
        }
        for (int ks = 0; ks < 2; ks++) {
            bf16x8 a = fragld(&sM[h][0][0], it * 16, ks * 32, 72);
            bf16x8 bb = fragld(&sXt[0][0], h * 64 + pt * 16, ks * 32, 72);
            acc = __builtin_amdgcn_mfma_f32_16x16x32_bf16(a, bb, acc, 0, 0, 0);
        }
        for (int rr = 0; rr < 4; rr++) {
            int i = it * 16 + q4 * 4 + rr;
            float v = acc[rr];
            float vn = __shfl_xor(v, 1);
            if (!(lane & 1)) {
                unsigned int pk = f2bf(v) | ((unsigned int)f2bf(vn) << 16);
                *(unsigned int*)(YBb + (rbase + i) * DI + pg) = pk;
            }
        }
    }
    size_t slbase = ((size_t)(b * NC + c)) * 16384;
#pragma unroll
    for (int u = 0; u < 8; u++) {
        int idx = wid * 8 + u;
        int ptl = idx >> 3, st = idx & 7;
        int h = ptl >> 2;
        f32x4 acc = {0.f, 0.f, 0.f, 0.f};
        for (int ks = 0; ks < 2; ks++) {
            int jb = ks * 32 + (lane >> 4) * 8;
            bf16x8 a = fragld(&sXt[0][0], ptl * 16, ks * 32, 72);
            bf16x8 aw;
#pragma unroll
            for (int t = 0; t < 8; t++) aw[t] = (short)f2bf(bf2f((unsigned short)a[t]) * s_w[h][jb + t]);
            bf16x8 bb = fragld(&sBt[0][0], st * 16, ks * 32, 72);
            acc = __builtin_amdgcn_mfma_f32_16x16x32_bf16(aw, bb, acc, 0, 0, 0);
        }
        int s = st * 16 + c16;
        for (int rr = 0; rr < 4; rr++) {
            int p = ptl * 16 + q4 * 4 + rr;
            float vv = acc[rr];
            float vn = __shfl_xor(vv, 1);
            if (!(lane & 1)) {
                unsigned int pk = f2bf(vv) | ((unsigned int)f2bf(vn) << 16);
                *(unsigned int*)(SL + slbase + (size_t)p * 128 + s) = pk;
            }
        }
    }
}

// ---------------- cross-chunk state scan ----------------
__global__ __launch_bounds__(256) void k_scan(unsigned short* __restrict__ SL,
                                              const float* __restrict__ TB) {
    int bid = blockIdx.x;
    int b = bid >> 6;
    int ps = (bid & 63) * 256 + threadIdx.x;
    int h = ps >> 13;
    const float* dAp = TB + (b * 2 + h) * NC;
    size_t base = (size_t)(b * NC) * 16384 + ps;
    float hacc = 0.f;
#pragma unroll 8
    for (int cc = 0; cc < NC; cc++) {
        size_t idx = base + (size_t)cc * 16384;
        float slv = bf2f(SL[idx]);
        SL[idx] = f2bf(hacc);
        hacc = hacc * dAp[cc] + slv;
    }
}

// ---------------- fused: Y_inter + gate*SiLU(z) + RMSNorm + out_proj + bf16 residual ----------------
__global__ __launch_bounds__(512, 2) void k_fused(
        const unsigned short* __restrict__ SL, const unsigned short* __restrict__ CBuf,
        const float* __restrict__ EB,
        const unsigned short* __restrict__ YBb, const unsigned short* __restrict__ ZXb,
        const float* __restrict__ NW, const unsigned short* __restrict__ OWb,
        unsigned short* __restrict__ Xb, float* __restrict__ OutF, int last) {
    __shared__ __attribute__((aligned(16))) unsigned short sH[128][136];
    __shared__ __attribute__((aligned(16))) unsigned short sE[128][136];
    float* sGf = (float*)&sH[0][0];                                   // [64][132] overlay
    unsigned short (*sG)[136] = (unsigned short (*)[136])&sE[0][0];   // [64][136] overlay

    int c = blockIdx.x, b = blockIdx.y;
    size_t rbase = (size_t)b * SEQ + c * QC;
    int tid = threadIdx.x;
    int wid = tid >> 6, lane = tid & 63;
    size_t base = ((size_t)(b * NC + c)) * 16384;
    for (int u = 0; u < 4; u++) {
        int e = u * 512 + tid;
        int row = e >> 4, cb8 = (e & 15) * 8;
        *(uint4*)&sH[row][cb8] = *(const uint4*)(SL + base + (size_t)row * 128 + cb8);
    }
    size_t cbbase = ((size_t)(b * NC + c)) * 8192;
    size_t ebase  = ((size_t)(b * NC + c)) * 128;
    for (int u = 0; u < 2; u++) {
        int idx8 = u * 512 + tid;          // uint4 index over 1024
        int i = idx8 >> 4, sc = (idx8 & 15) * 8;
        uint4 cv = *(const uint4*)(CBuf + cbbase + (size_t)i * 128 + sc);
        float e0 = EB[ebase + i], e1 = EB[ebase + 64 + i];
        unsigned int w[4] = {cv.x, cv.y, cv.z, cv.w};
        uint4 o0, o1;
        unsigned int* po0 = &o0.x;
        unsigned int* po1 = &o1.x;
#pragma unroll
        for (int t = 0; t < 4; t++) {
            float lo = bf2f((unsigned short)(w[t] & 0xffff));
            float hi = bf2f((unsigned short)(w[t] >> 16));
            po0[t] = f2bf(lo * e0) | ((unsigned int)f2bf(hi * e0) << 16);
            po1[t] = f2bf(lo * e1) | ((unsigned int)f2bf(hi * e1) << 16);
        }
        *(uint4*)&sE[i][sc] = o0;
        *(uint4*)&sE[64 + i][sc] = o1;
    }
    __syncthreads();
    int q4 = lane >> 4, c16 = lane & 15;

    float yv[4][4];
    int tit[4], tpg[4];
#pragma unroll
    for (int u = 0; u < 4; u++) {
        int idx = wid * 4 + u;
        int h = idx >> 4, tt = idx & 15;
        int it = tt >> 2, pt = tt & 3;
        f32x4 acc = {0.f, 0.f, 0.f, 0.f};
        for (int ks = 0; ks < 4; ks++) {
            bf16x8 a = fragld(&sE[0][0], h * 64 + it * 16, ks * 32, 136);
            bf16x8 bb = fragld(&sH[0][0], h * 64 + pt * 16, ks * 32, 136);
            acc = __builtin_amdgcn_mfma_f32_16x16x32_bf16(a, bb, acc, 0, 0, 0);
        }
        int pg = h * 64 + pt * 16 + c16;
        tit[u] = it; tpg[u] = pg;
        for (int rr = 0; rr < 4; rr++) {
            int i = it * 16 + q4 * 4 + rr;
            float y = acc[rr] + bf2f(YBb[(rbase + i) * DI + pg]);
            float z = bf2f(ZXb[(rbase + i) * ZW + pg]);
            yv[u][rr] = y * (z / (1.f + __expf(-z)));
        }
    }
    __syncthreads();
#pragma unroll
    for (int u = 0; u < 4; u++)
        for (int rr = 0; rr < 4; rr++) {
            int i = tit[u] * 16 + q4 * 4 + rr;
            sGf[i * 132 + tpg[u]] = yv[u][rr];
        }
    __syncthreads();
    {
        int row = tid >> 3, p0 = (tid & 7) * 16;
        float g[16];
        float ss = 0.f;
        for (int t2 = 0; t2 < 16; t2++) { g[t2] = sGf[row * 132 + p0 + t2]; ss += g[t2] * g[t2]; }
        ss += __shfl_xor(ss, 1);
        ss += __shfl_xor(ss, 2);
        ss += __shfl_xor(ss, 4);
        float rms = rsqrtf(ss * (1.f / 128.f) + 1e-5f);
        for (int t2 = 0; t2 < 16; t2 += 2) {
            unsigned int pk = f2bf(g[t2] * rms * NW[p0 + t2]) |
                              ((unsigned int)f2bf(g[t2 + 1] * rms * NW[p0 + t2 + 1]) << 16);
            *(unsigned int*)&sG[row][p0 + t2] = pk;
        }
    }
    __syncthreads();
#pragma unroll
    for (int u = 0; u < 2; u++) {
        int t = wid * 2 + u;
        int mt = t >> 2, nt = t & 3;
        f32x4 acc = {0.f, 0.f, 0.f, 0.f};
        for (int ks = 0; ks < 4; ks++) {
            bf16x8 a = fragld(&sG[0][0], mt * 16, ks * 32, 136);
            bf16x8 bb = *(const bf16x8*)(OWb + (size_t)(nt * 16 + c16) * 128 + ks * 32 + q4 * 8);
            acc = __builtin_amdgcn_mfma_f32_16x16x32_bf16(a, bb, acc, 0, 0, 0);
        }
        for (int rr = 0; rr < 4; rr++) {
            int m = mt * 16 + q4 * 4 + rr;
            int n = nt * 16 + c16;
            size_t o = (rbase + m) * DM + n;
            float v = bf2f(Xb[o]) + acc[rr];
            if (last) {
                OutF[o] = v;
            } else {
                float vn = __shfl_xor(v, 1);
                if (!(lane & 1)) {
                    unsigned int pk = f2bf(v) | ((unsigned int)f2bf(vn) << 16);
                    *(unsigned int*)(Xb + o) = pk;
                }
            }
        }
    }
}

extern "C" void kernel_launch(void* const* d_in, const int* in_sizes, int n_in,
                              void* d_out, int out_size, void* d_ws, size_t ws_size,
                              hipStream_t stream) {
    const float* x       = (const float*)d_in[0];
    const float* in_w    = (const float*)d_in[1];
    const float* conv_w  = (const float*)d_in[2];
    const float* conv_b  = (const float*)d_in[3];
    const float* dt_bias = (const float*)d_in[4];
    const float* A_log   = (const float*)d_in[5];
    const float* Dp      = (const float*)d_in[6];
    const float* norm_w  = (const float*)d_in[7];
    const float* out_w   = (const float*)d_in[8];
    float* out = (float*)d_out;
    float* ws  = (float*)d_ws;

    float* dt = ws;                                        // NR*2 f32
    float* tb = dt + (size_t)NR * 2;                       // 1024 f32
    float* eb = tb + 1024;                                 // 8*64*128 f32
    unsigned short* zxb  = (unsigned short*)(eb + (size_t)B_SZ * NC * 128);
    unsigned short* ybb  = zxb + (size_t)NR * ZW;          // NR*128
    unsigned short* sl   = ybb + (size_t)NR * DI;          // 8*64*16384
    unsigned short* cbuf = sl + (size_t)B_SZ * NC * 16384; // 8*64*8192
    unsigned short* xb   = cbuf + (size_t)B_SZ * NC * 8192;// NR*64
    unsigned short* wb   = xb + (size_t)NR * DM;           // 4*576*64
    unsigned short* owb  = wb + (size_t)4 * WPAD * 64;     // 4*64*128

    k_wcvt<<<(4 * WPAD * 64 + 255) / 256, 256, 0, stream>>>(in_w, out_w, wb, owb);
    k_xcvt<<<NR * DM / 1024, 256, 0, stream>>>(x, xb);

    for (int layer = 0; layer < 4; layer++) {
        k_inproj<<<dim3(NR / 256, 9), 256, 0, stream>>>(xb, wb + (size_t)layer * WPAD * 64, zxb, dt);
        k_chunk1<<<dim3(NC, B_SZ), 512, 0, stream>>>(zxb, dt,
                conv_w + (size_t)layer * CD * 4, conv_b + (size_t)layer * CD,
                dt_bias + layer * NH, A_log + layer * NH, Dp + layer * NH,
                sl, cbuf, eb, tb, ybb);
        k_scan<<<512, 256, 0, stream>>>(sl, tb);
        k_fused<<<dim3(NC, B_SZ), 512, 0, stream>>>(sl, cbuf, eb, ybb, zxb,
                norm_w + layer * DI, owb + (size_t)layer * 64 * 128, xb, out,
                (layer == 3) ? 1 : 0);
    }
}